// Round 2
// baseline (2075.080 us; speedup 1.0000x reference)
//
#include <hip/hip_runtime.h>
#include <cstddef>

#define NPTS 10000
#define TDIM 64
#define CINDIM 64
#define FDIM 64
#define HIDDIM 128
#define SDIM 8

// ---------------------------------------------------------------------------
// Pre-transpose weights into workspace:
//   w1t[k][c][f]  (3*64*64)    from W1[f][c][k]
//   w2t[k][c][f]  (3*128*64)   from W2[f][c][k]
//   wfct[c][h]    (128*128)    from Wfc[h][c]
// so per-block LDS staging in the compute kernels reads contiguous memory.
// ---------------------------------------------------------------------------
__global__ __launch_bounds__(256) void transpose_w_kernel(
    const float* __restrict__ W1, const float* __restrict__ W2,
    const float* __restrict__ Wfc, float* __restrict__ w1t,
    float* __restrict__ w2t, float* __restrict__ wfct) {
  const int i = blockIdx.x * 256 + threadIdx.x;
  if (i < 3 * 64 * 64) {
    const int k = i >> 12, c = (i >> 6) & 63, f = i & 63;
    w1t[i] = W1[f * 192 + c * 3 + k];
  }
  if (i < 3 * 128 * 64) {
    const int k = i >> 13, c = (i >> 6) & 127, f = i & 63;
    w2t[i] = W2[f * 384 + c * 3 + k];
  }
  if (i < 128 * 128) {
    const int c = i >> 7, hh = i & 127;
    wfct[i] = Wfc[hh * 128 + c];
  }
}

// ---------------------------------------------------------------------------
// conv1: x[N,T,64] -> h[N,T,64], causal dilated (K=3, dil=2), relu(y + b1).
// y[n,t,f] = sum_{k,c} W1[f,c,k] * x[n, t-4+2k, c]   (x padded left with 4 zeros)
// One block per n. xs row stride 65 (odd) -> broadcast reads hit 2 banks (free).
// ---------------------------------------------------------------------------
__global__ __launch_bounds__(256) void conv1_kernel(
    const float* __restrict__ x, const float* __restrict__ w1t,
    const float* __restrict__ b1, float* __restrict__ h) {
  __shared__ float xs[68 * 65];       // row r = t'+4 (rows 0..3 are zero pad)
  __shared__ float wt[3 * 64 * 64];   // wt[k][c][f]
  const int n = blockIdx.x;
  const int tid = threadIdx.x;
  const float* xn = x + (size_t)n * (TDIM * CINDIM);
  for (int i = tid; i < 68 * 64; i += 256) {
    const int r = i >> 6, c = i & 63;
    xs[r * 65 + c] = (r < 4) ? 0.f : xn[i - 4 * 64];
  }
  for (int i = tid; i < (3 * 64 * 64) / 4; i += 256)
    ((float4*)wt)[i] = ((const float4*)w1t)[i];
  __syncthreads();

  const int f4 = tid & 15;   // f = 4*f4
  const int tr = tid >> 4;   // 0..15 ; thread handles t = tr + 16*j
  const float4 bias = *(const float4*)&b1[4 * f4];
  float4 acc[4];
#pragma unroll
  for (int j = 0; j < 4; ++j) acc[j] = bias;

  for (int c = 0; c < 64; ++c) {
    const float4 w0 = *(const float4*)&wt[c * 64 + 4 * f4];
    const float4 w1 = *(const float4*)&wt[4096 + c * 64 + 4 * f4];
    const float4 w2 = *(const float4*)&wt[8192 + c * 64 + 4 * f4];
#pragma unroll
    for (int j = 0; j < 4; ++j) {
      const int t = tr + 16 * j;
      const float xa = xs[(t + 0) * 65 + c];  // k=0 -> row t
      const float xb = xs[(t + 2) * 65 + c];  // k=1 -> row t+2
      const float xc = xs[(t + 4) * 65 + c];  // k=2 -> row t+4
      acc[j].x = fmaf(w0.x, xa, fmaf(w1.x, xb, fmaf(w2.x, xc, acc[j].x)));
      acc[j].y = fmaf(w0.y, xa, fmaf(w1.y, xb, fmaf(w2.y, xc, acc[j].y)));
      acc[j].z = fmaf(w0.z, xa, fmaf(w1.z, xb, fmaf(w2.z, xc, acc[j].z)));
      acc[j].w = fmaf(w0.w, xa, fmaf(w1.w, xb, fmaf(w2.w, xc, acc[j].w)));
    }
  }
  float* hn = h + (size_t)n * (TDIM * FDIM);
#pragma unroll
  for (int j = 0; j < 4; ++j) {
    const int t = tr + 16 * j;
    float4 v = acc[j];
    v.x = fmaxf(v.x, 0.f); v.y = fmaxf(v.y, 0.f);
    v.z = fmaxf(v.z, 0.f); v.w = fmaxf(v.w, 0.f);
    *(float4*)&hn[t * FDIM + 4 * f4] = v;
  }
}

// ---------------------------------------------------------------------------
// Neighbor gather + masked mean. One wave per (t,n) pair; lane = feature.
// agg[n,t,f] = mean_{s: mask} h[idx[t,n,s], t, f]   (fallback: h[n,t,f])
// NOTE: neighbor_mask (bool in reference) arrives as int32 per harness rules.
// ---------------------------------------------------------------------------
__global__ __launch_bounds__(256) void gather_kernel(
    const float* __restrict__ h, const int* __restrict__ nidx,
    const int* __restrict__ nmask, float* __restrict__ agg) {
  const long pair = (long)blockIdx.x * 4 + (threadIdx.x >> 6);
  const int lane = threadIdx.x & 63;
  const int t = (int)(pair / NPTS);
  const int n = (int)(pair - (long)t * NPTS);
  const size_t base = ((size_t)t * NPTS + n) * SDIM;
  float acc = 0.f, cnt = 0.f;
#pragma unroll
  for (int s = 0; s < SDIM; ++s) {
    if (nmask[base + s] != 0) {
      const int nb = nidx[base + s];
      acc += h[((size_t)nb * TDIM + t) * FDIM + lane];  // 256B coalesced row
      cnt += 1.f;
    }
  }
  float val;
  if (cnt > 0.f) val = acc / cnt;
  else val = h[((size_t)n * TDIM + t) * FDIM + lane];
  agg[((size_t)n * TDIM + t) * FDIM + lane] = val;
}

// ---------------------------------------------------------------------------
// FC: z[row,h] = relu( sum_c [h|agg][row,c] * Wfc[h,c] + bfc[h] ), rows = N*T.
// 32 rows per block; Wfc chunked over c (2 chunks of 64) in LDS.
// ---------------------------------------------------------------------------
__global__ __launch_bounds__(256) void fc_kernel(
    const float* __restrict__ h, const float* __restrict__ agg,
    const float* __restrict__ wfct, const float* __restrict__ bfc,
    float* __restrict__ z) {
  __shared__ float wt[64 * 132];    // wt[c][h], padded stride 132
  __shared__ float comb[32 * 128];  // comb[r][c]
  const int rowbase = blockIdx.x * 32;
  const int tid = threadIdx.x;
  for (int i = tid; i < 32 * 16; i += 256) {
    const int r = i >> 4, c4 = i & 15;
    ((float4*)&comb[r * 128])[c4] =
        ((const float4*)&h[(size_t)(rowbase + r) * 64])[c4];
    ((float4*)&comb[r * 128 + 64])[c4] =
        ((const float4*)&agg[(size_t)(rowbase + r) * 64])[c4];
  }
  const int h4 = tid & 31;  // h = 4*h4
  const int rr = tid >> 5;  // 0..7 ; rows rr + 8*j
  const float4 bias = *(const float4*)&bfc[4 * h4];
  float4 acc[4];
#pragma unroll
  for (int j = 0; j < 4; ++j) acc[j] = bias;

  for (int cc = 0; cc < 128; cc += 64) {
    __syncthreads();
    for (int i = tid; i < 64 * 32; i += 256) {  // 2048 float4s
      const int c = i >> 5, g = i & 31;
      *(float4*)&wt[c * 132 + 4 * g] =
          *(const float4*)&wfct[(size_t)(cc + c) * 128 + 4 * g];
    }
    __syncthreads();
    for (int c = 0; c < 64; ++c) {
      const float4 w = *(const float4*)&wt[c * 132 + 4 * h4];
#pragma unroll
      for (int j = 0; j < 4; ++j) {
        const float v = comb[(rr + 8 * j) * 128 + cc + c];
        acc[j].x = fmaf(w.x, v, acc[j].x);
        acc[j].y = fmaf(w.y, v, acc[j].y);
        acc[j].z = fmaf(w.z, v, acc[j].z);
        acc[j].w = fmaf(w.w, v, acc[j].w);
      }
    }
  }
#pragma unroll
  for (int j = 0; j < 4; ++j) {
    const size_t row = rowbase + rr + 8 * j;
    float4 v = acc[j];
    v.x = fmaxf(v.x, 0.f); v.y = fmaxf(v.y, 0.f);
    v.z = fmaxf(v.z, 0.f); v.w = fmaxf(v.w, 0.f);
    *(float4*)&z[row * 128 + 4 * h4] = v;
  }
}

// ---------------------------------------------------------------------------
// conv2: z[N,T,128] -> out[N,T,64], causal dilated (K=3, dil=2), relu(y + b2).
// One block per n; W2 chunked over c (4 chunks of 32) in LDS.
// ---------------------------------------------------------------------------
__global__ __launch_bounds__(256) void conv2_kernel(
    const float* __restrict__ z, const float* __restrict__ w2t,
    const float* __restrict__ b2, float* __restrict__ out) {
  __shared__ float zs[68 * 129];    // row r = t'+4, stride 129 (odd)
  __shared__ float wt[3 * 32 * 64]; // chunk: wt[k][c][f]
  const int n = blockIdx.x;
  const int tid = threadIdx.x;
  const float* zn = z + (size_t)n * (TDIM * HIDDIM);
  for (int i = tid; i < 68 * 128; i += 256) {
    const int r = i >> 7, c = i & 127;
    zs[r * 129 + c] = (r < 4) ? 0.f : zn[i - 4 * 128];
  }
  const int f4 = tid & 15;
  const int tr = tid >> 4;
  const float4 bias = *(const float4*)&b2[4 * f4];
  float4 acc[4];
#pragma unroll
  for (int j = 0; j < 4; ++j) acc[j] = bias;

  for (int cc = 0; cc < 128; cc += 32) {
    __syncthreads();
    for (int i = tid; i < (3 * 32 * 64) / 4; i += 256) {  // 1536 float4s
      const int k = i / 512, rem = i - k * 512;
      ((float4*)wt)[i] =
          ((const float4*)(w2t + (size_t)k * 8192 + (size_t)cc * 64))[rem];
    }
    __syncthreads();
    for (int c = 0; c < 32; ++c) {
      const float4 w0 = *(const float4*)&wt[c * 64 + 4 * f4];
      const float4 w1 = *(const float4*)&wt[2048 + c * 64 + 4 * f4];
      const float4 w2 = *(const float4*)&wt[4096 + c * 64 + 4 * f4];
      const int ci = cc + c;
#pragma unroll
      for (int j = 0; j < 4; ++j) {
        const int t = tr + 16 * j;
        const float xa = zs[(t + 0) * 129 + ci];
        const float xb = zs[(t + 2) * 129 + ci];
        const float xc = zs[(t + 4) * 129 + ci];
        acc[j].x = fmaf(w0.x, xa, fmaf(w1.x, xb, fmaf(w2.x, xc, acc[j].x)));
        acc[j].y = fmaf(w0.y, xa, fmaf(w1.y, xb, fmaf(w2.y, xc, acc[j].y)));
        acc[j].z = fmaf(w0.z, xa, fmaf(w1.z, xb, fmaf(w2.z, xc, acc[j].z)));
        acc[j].w = fmaf(w0.w, xa, fmaf(w1.w, xb, fmaf(w2.w, xc, acc[j].w)));
      }
    }
  }
  float* on = out + (size_t)n * (TDIM * FDIM);
#pragma unroll
  for (int j = 0; j < 4; ++j) {
    const int t = tr + 16 * j;
    float4 v = acc[j];
    v.x = fmaxf(v.x, 0.f); v.y = fmaxf(v.y, 0.f);
    v.z = fmaxf(v.z, 0.f); v.w = fmaxf(v.w, 0.f);
    *(float4*)&on[t * FDIM + 4 * f4] = v;
  }
}

// ---------------------------------------------------------------------------
// Workspace layout (floats): [w1t 12288][w2t 24576][wfct 16384]
//                            [agg N*T*64][z N*T*128]   total ~470 MB.
// h lives in d_out (conv2 only reads z, then overwrites d_out with the result).
// ---------------------------------------------------------------------------
extern "C" void kernel_launch(void* const* d_in, const int* in_sizes, int n_in,
                              void* d_out, int out_size, void* d_ws, size_t ws_size,
                              hipStream_t stream) {
  (void)in_sizes; (void)n_in; (void)out_size; (void)ws_size;
  const float* x    = (const float*)d_in[0];
  const float* W1   = (const float*)d_in[1];
  const float* b1   = (const float*)d_in[2];
  const float* Wfc  = (const float*)d_in[3];
  const float* bfc  = (const float*)d_in[4];
  const float* W2   = (const float*)d_in[5];
  const float* b2   = (const float*)d_in[6];
  const int* nidx   = (const int*)d_in[7];
  const int* nmask  = (const int*)d_in[8];
  float* out = (float*)d_out;

  float* wsf  = (float*)d_ws;
  float* w1t  = wsf;
  float* w2t  = w1t + 3 * 64 * 64;
  float* wfct = w2t + 3 * 128 * 64;
  float* agg  = wfct + 128 * 128;
  float* z    = agg + (size_t)NPTS * TDIM * FDIM;

  float* h = out;  // stage h in d_out

  transpose_w_kernel<<<96, 256, 0, stream>>>(W1, W2, Wfc, w1t, w2t, wfct);
  conv1_kernel<<<NPTS, 256, 0, stream>>>(x, w1t, b1, h);
  gather_kernel<<<(NPTS * TDIM) / 4, 256, 0, stream>>>(h, nidx, nmask, agg);
  fc_kernel<<<(NPTS * TDIM) / 32, 256, 0, stream>>>(h, agg, wfct, bfc, z);
  conv2_kernel<<<NPTS, 256, 0, stream>>>(z, w2t, b2, out);
}

// Round 4
// 953.515 us; speedup vs baseline: 2.1762x; 2.1762x over previous
//
#include <hip/hip_runtime.h>
#include <cstddef>
#include <cstdint>

#define NPTS 10000
#define TDIM 64
#define CINDIM 64
#define FDIM 64
#define HIDDIM 128
#define SDIM 8
#define NG 4  // n's per block in matmul kernels

typedef _Float16 f16;
typedef _Float16 f16x2 __attribute__((ext_vector_type(2)));
typedef _Float16 f16x4 __attribute__((ext_vector_type(4)));
typedef _Float16 f16x8 __attribute__((ext_vector_type(8)));
typedef float f32x4 __attribute__((ext_vector_type(4)));

#define MFMA16(a, b, c) __builtin_amdgcn_mfma_f32_16x16x32_f16((a), (b), (c), 0, 0, 0)

static __device__ __forceinline__ f16x2 pk(float a, float b) {
  return __builtin_bit_cast(f16x2, __builtin_amdgcn_cvt_pkrtz(a, b));
}
// pack 8 fp32 -> f16x8 (RTZ, hot path: conv1 A-fragments)
static __device__ __forceinline__ f16x8 pack8(f32x4 p, f32x4 q) {
  f16x2 h0 = pk(p[0], p[1]), h1 = pk(p[2], p[3]);
  f16x2 h2 = pk(q[0], q[1]), h3 = pk(q[2], q[3]);
  f16x4 lo = __builtin_shufflevector(h0, h1, 0, 1, 2, 3);
  f16x4 hi = __builtin_shufflevector(h2, h3, 0, 1, 2, 3);
  return __builtin_shufflevector(lo, hi, 0, 1, 2, 3, 4, 5, 6, 7);
}
// bias + relu + RNE-convert 4 accum values -> f16x4
static __device__ __forceinline__ f16x4 pack4_relu(f32x4 v, f32x4 bias) {
  f16x4 r;
  r[0] = (f16)fmaxf(v[0] + bias[0], 0.f);
  r[1] = (f16)fmaxf(v[1] + bias[1], 0.f);
  r[2] = (f16)fmaxf(v[2] + bias[2], 0.f);
  r[3] = (f16)fmaxf(v[3] + bias[3], 0.f);
  return r;
}

// ---------------------------------------------------------------------------
// prep: split weights into hi/lo fp16 and pre-shuffle into per-lane-contiguous
// MFMA A-operand fragment order. A-frag (16x16x32): row(f) = lane&15,
// k-col = (lane>>4)*8 + j. Layout: [slice][ks][lane][j].
//   conv1 K-index kk = k*64 + c   (K=192, 6 ks)
//   fc    kk = c                  (K=128, 4 ks;  c<64 -> h, c>=64 -> agg)
//   conv2 kk = k*128 + c          (K=384, 12 ks)
// ---------------------------------------------------------------------------
__global__ __launch_bounds__(256) void prep_kernel(
    const float* __restrict__ W1, const float* __restrict__ Wfc,
    const float* __restrict__ W2,
    f16* __restrict__ w1h, f16* __restrict__ w1l,
    f16* __restrict__ wfh, f16* __restrict__ wfl,
    f16* __restrict__ w2h, f16* __restrict__ w2l) {
  const int idx = blockIdx.x * 256 + threadIdx.x;
  if (idx < 4 * 6 * 64 * 8) {  // w1: 12288
    const int s = idx / 3072, rem = idx % 3072;
    const int ks = rem / 512, r2 = rem % 512;
    const int l = r2 >> 3, j = r2 & 7;
    const int kk = ks * 32 + ((l >> 4) << 3) + j;
    const int k = kk >> 6, c = kk & 63, f = s * 16 + (l & 15);
    const float v = W1[f * 192 + c * 3 + k];
    const f16 hi = (f16)v;
    w1h[idx] = hi;
    w1l[idx] = (f16)(v - (float)hi);
  }
  if (idx < 8 * 4 * 64 * 8) {  // wfc: 16384
    const int s = idx / 2048, rem = idx % 2048;
    const int ks = rem / 512, r2 = rem % 512;
    const int l = r2 >> 3, j = r2 & 7;
    const int kk = ks * 32 + ((l >> 4) << 3) + j;
    const int hc = s * 16 + (l & 15);
    const float v = Wfc[hc * 128 + kk];
    const f16 hi = (f16)v;
    wfh[idx] = hi;
    wfl[idx] = (f16)(v - (float)hi);
  }
  if (idx < 4 * 12 * 64 * 8) {  // w2: 24576
    const int s = idx / 6144, rem = idx % 6144;
    const int ks = rem / 512, r2 = rem % 512;
    const int l = r2 >> 3, j = r2 & 7;
    const int kk = ks * 32 + ((l >> 4) << 3) + j;
    const int k = kk >> 7, c = kk & 127, f = s * 16 + (l & 15);
    const float v = W2[f * 384 + c * 3 + k];
    const f16 hi = (f16)v;
    w2h[idx] = hi;
    w2l[idx] = (f16)(v - (float)hi);
  }
}

// ---------------------------------------------------------------------------
// conv1: h[n,t,f] = relu(b1[f] + sum_{k,c} W1[f,c,k] * x[n, t-4+2k, c])
// D[f][t] = Wfrag * Act^T. Wave w owns f-slice [16w,16w+16); 4 t-frags of 16.
// B-frag: lane reads act row t0+(lane&15), 8 contig k at ks*32+(lane>>4)*8.
// No LDS, no barriers; weights in VGPRs across the NG n-loop.
// ---------------------------------------------------------------------------
__global__ __launch_bounds__(256) void conv1_kernel(
    const float* __restrict__ x, const f16* __restrict__ w1h,
    const f16* __restrict__ w1l, const float* __restrict__ b1,
    f16* __restrict__ h16) {
  const int tid = threadIdx.x;
  const int w = tid >> 6, lane = tid & 63;
  const int rl = lane & 15, ch = lane >> 4;
  const f16x8 fz = {(f16)0, (f16)0, (f16)0, (f16)0, (f16)0, (f16)0, (f16)0, (f16)0};
  f16x8 wh[6], wl[6];
#pragma unroll
  for (int ks = 0; ks < 6; ++ks) {
    wh[ks] = *(const f16x8*)&w1h[((w * 6 + ks) * 64 + lane) * 8];
    wl[ks] = *(const f16x8*)&w1l[((w * 6 + ks) * 64 + lane) * 8];
  }
  const int f0 = w * 16 + ch * 4;
  const f32x4 bias = *(const f32x4*)&b1[f0];
  for (int g = 0; g < NG; ++g) {
    const int n = blockIdx.x * NG + g;
    const float* xn = x + (size_t)n * (TDIM * CINDIM);
    f32x4 acc[4];
#pragma unroll
    for (int tf = 0; tf < 4; ++tf) acc[tf] = (f32x4){0.f, 0.f, 0.f, 0.f};
#pragma unroll
    for (int ks = 0; ks < 6; ++ks) {
      const int k = ks >> 1;
      const int c0 = (ks & 1) * 32 + ch * 8;
      f16x8 bf[4];
#pragma unroll
      for (int tf = 0; tf < 4; ++tf) {
        const int r = tf * 16 + rl - 4 + 2 * k;  // causal left-pad of 4
        if (r < 0) {
          bf[tf] = fz;
        } else {
          const f32x4 p = *(const f32x4*)&xn[r * 64 + c0];
          const f32x4 q = *(const f32x4*)&xn[r * 64 + c0 + 4];
          bf[tf] = pack8(p, q);
        }
      }
#pragma unroll
      for (int tf = 0; tf < 4; ++tf) acc[tf] = MFMA16(wh[ks], bf[tf], acc[tf]);
#pragma unroll
      for (int tf = 0; tf < 4; ++tf) acc[tf] = MFMA16(wl[ks], bf[tf], acc[tf]);
    }
#pragma unroll
    for (int tf = 0; tf < 4; ++tf) {
      const int t = tf * 16 + rl;
      *(f16x4*)&h16[((size_t)n * 64 + t) * 64 + f0] = pack4_relu(acc[tf], bias);
    }
  }
}

// ---------------------------------------------------------------------------
// gather: agg[n,t,:] = masked-mean_s h[idx[t,n,s], t, :] (fallback self row).
// Half-wave (32 lanes) per (t,n) pair; lane = u32 = 2 fp16 features.
// ---------------------------------------------------------------------------
__global__ __launch_bounds__(256) void gather_kernel(
    const f16* __restrict__ h16, const int* __restrict__ nidx,
    const int* __restrict__ nmask, f16* __restrict__ agg16) {
  const int tid = threadIdx.x;
  const long p = (long)blockIdx.x * 8 + (tid >> 5);
  const int lane32 = tid & 31;
  const int t = (int)(p / NPTS);
  const int n = (int)(p - (long)t * NPTS);
  const uint32_t* h32 = (const uint32_t*)h16;
  uint32_t* agg32 = (uint32_t*)agg16;
  const size_t base8 = ((size_t)t * NPTS + n) * SDIM;
  float ax = 0.f, ay = 0.f;
  int cnt = 0;
#pragma unroll
  for (int s = 0; s < SDIM; ++s) {
    if (nmask[base8 + s] != 0) {
      const int nb = nidx[base8 + s];
      const uint32_t u = h32[((size_t)nb * 64 + t) * 32 + lane32];
      const f16x2 hv = *(const f16x2*)&u;
      ax += (float)hv[0];
      ay += (float)hv[1];
      ++cnt;
    }
  }
  f16x2 outv;
  if (cnt > 0) {
    const float inv = 1.f / (float)cnt;
    outv[0] = (f16)(ax * inv);
    outv[1] = (f16)(ay * inv);
  } else {
    const uint32_t u = h32[((size_t)n * 64 + t) * 32 + lane32];
    outv = *(const f16x2*)&u;
  }
  agg32[((size_t)n * 64 + t) * 32 + lane32] = *(const uint32_t*)&outv;
}

// ---------------------------------------------------------------------------
// fc: z[row,hc] = relu(bfc[hc] + sum_c [h|agg][row,c] * Wfc[hc,c])
// Wave w owns hc-slices {2w, 2w+1} (32 cols). K=128: ks 0,1 from h16,
// ks 2,3 from agg16.
// ---------------------------------------------------------------------------
__global__ __launch_bounds__(256) void fc_kernel(
    const f16* __restrict__ h16, const f16* __restrict__ agg16,
    const f16* __restrict__ wfh, const f16* __restrict__ wfl,
    const float* __restrict__ bfc, f16* __restrict__ z16) {
  const int tid = threadIdx.x;
  const int w = tid >> 6, lane = tid & 63;
  const int rl = lane & 15, ch = lane >> 4;
  f16x8 whA[4], wlA[4], whB[4], wlB[4];
#pragma unroll
  for (int ks = 0; ks < 4; ++ks) {
    whA[ks] = *(const f16x8*)&wfh[(((2 * w) * 4 + ks) * 64 + lane) * 8];
    wlA[ks] = *(const f16x8*)&wfl[(((2 * w) * 4 + ks) * 64 + lane) * 8];
    whB[ks] = *(const f16x8*)&wfh[(((2 * w + 1) * 4 + ks) * 64 + lane) * 8];
    wlB[ks] = *(const f16x8*)&wfl[(((2 * w + 1) * 4 + ks) * 64 + lane) * 8];
  }
  const int hA = 2 * w * 16 + ch * 4, hB = hA + 16;
  const f32x4 biasA = *(const f32x4*)&bfc[hA];
  const f32x4 biasB = *(const f32x4*)&bfc[hB];
  for (int g = 0; g < NG; ++g) {
    const int n = blockIdx.x * NG + g;
    f32x4 accA[4], accB[4];
#pragma unroll
    for (int tf = 0; tf < 4; ++tf) {
      accA[tf] = (f32x4){0.f, 0.f, 0.f, 0.f};
      accB[tf] = (f32x4){0.f, 0.f, 0.f, 0.f};
    }
#pragma unroll
    for (int ks = 0; ks < 4; ++ks) {
      const f16* src = (ks < 2) ? h16 : agg16;
      const int c0 = (ks & 1) * 32 + ch * 8;
      f16x8 bf[4];
#pragma unroll
      for (int tf = 0; tf < 4; ++tf) {
        const int t = tf * 16 + rl;
        bf[tf] = *(const f16x8*)&src[((size_t)n * 64 + t) * 64 + c0];
      }
#pragma unroll
      for (int tf = 0; tf < 4; ++tf) accA[tf] = MFMA16(whA[ks], bf[tf], accA[tf]);
#pragma unroll
      for (int tf = 0; tf < 4; ++tf) accA[tf] = MFMA16(wlA[ks], bf[tf], accA[tf]);
#pragma unroll
      for (int tf = 0; tf < 4; ++tf) accB[tf] = MFMA16(whB[ks], bf[tf], accB[tf]);
#pragma unroll
      for (int tf = 0; tf < 4; ++tf) accB[tf] = MFMA16(wlB[ks], bf[tf], accB[tf]);
    }
#pragma unroll
    for (int tf = 0; tf < 4; ++tf) {
      const int t = tf * 16 + rl;
      *(f16x4*)&z16[((size_t)n * 64 + t) * 128 + hA] = pack4_relu(accA[tf], biasA);
      *(f16x4*)&z16[((size_t)n * 64 + t) * 128 + hB] = pack4_relu(accB[tf], biasB);
    }
  }
}

// ---------------------------------------------------------------------------
// conv2: out[n,t,f] = relu(b2[f] + sum_{k,c} W2[f,c,k] * z[n, t-4+2k, c])
// K=384 (12 ks). Output fp32 (final). Weights: 96 VGPR.
// ---------------------------------------------------------------------------
__global__ __launch_bounds__(256) void conv2_kernel(
    const f16* __restrict__ z16, const f16* __restrict__ w2h,
    const f16* __restrict__ w2l, const float* __restrict__ b2,
    float* __restrict__ out) {
  const int tid = threadIdx.x;
  const int w = tid >> 6, lane = tid & 63;
  const int rl = lane & 15, ch = lane >> 4;
  const f16x8 fz = {(f16)0, (f16)0, (f16)0, (f16)0, (f16)0, (f16)0, (f16)0, (f16)0};
  f16x8 wh[12], wl[12];
#pragma unroll
  for (int ks = 0; ks < 12; ++ks) {
    wh[ks] = *(const f16x8*)&w2h[((w * 12 + ks) * 64 + lane) * 8];
    wl[ks] = *(const f16x8*)&w2l[((w * 12 + ks) * 64 + lane) * 8];
  }
  const int f0 = w * 16 + ch * 4;
  const f32x4 bias = *(const f32x4*)&b2[f0];
  for (int g = 0; g < NG; ++g) {
    const int n = blockIdx.x * NG + g;
    const f16* zn = z16 + (size_t)n * (TDIM * HIDDIM);
    f32x4 acc[4];
#pragma unroll
    for (int tf = 0; tf < 4; ++tf) acc[tf] = (f32x4){0.f, 0.f, 0.f, 0.f};
#pragma unroll
    for (int ks = 0; ks < 12; ++ks) {
      const int k = ks >> 2;
      const int c0 = (ks & 3) * 32 + ch * 8;
      f16x8 bf[4];
#pragma unroll
      for (int tf = 0; tf < 4; ++tf) {
        const int r = tf * 16 + rl - 4 + 2 * k;
        if (r < 0) {
          bf[tf] = fz;
        } else {
          bf[tf] = *(const f16x8*)&zn[r * 128 + c0];
        }
      }
#pragma unroll
      for (int tf = 0; tf < 4; ++tf) acc[tf] = MFMA16(wh[ks], bf[tf], acc[tf]);
#pragma unroll
      for (int tf = 0; tf < 4; ++tf) acc[tf] = MFMA16(wl[ks], bf[tf], acc[tf]);
    }
#pragma unroll
    for (int tf = 0; tf < 4; ++tf) {
      const int t = tf * 16 + rl;
      f32x4 v;
      v[0] = fmaxf(acc[tf][0] + bias[0], 0.f);
      v[1] = fmaxf(acc[tf][1] + bias[1], 0.f);
      v[2] = fmaxf(acc[tf][2] + bias[2], 0.f);
      v[3] = fmaxf(acc[tf][3] + bias[3], 0.f);
      *(f32x4*)&out[((size_t)n * 64 + t) * 64 + f0] = v;
    }
  }
}

// ---------------------------------------------------------------------------
// Workspace (f16 units):
//   w1h/w1l 12288 each | wfh/wfl 16384 each | w2h/w2l 24576 each
//   h16 40.96M | agg16 40.96M | z16 81.92M   -> total ~328 MB
// ---------------------------------------------------------------------------
extern "C" void kernel_launch(void* const* d_in, const int* in_sizes, int n_in,
                              void* d_out, int out_size, void* d_ws, size_t ws_size,
                              hipStream_t stream) {
  (void)in_sizes; (void)n_in; (void)out_size; (void)ws_size;
  const float* x   = (const float*)d_in[0];
  const float* W1  = (const float*)d_in[1];
  const float* b1  = (const float*)d_in[2];
  const float* Wfc = (const float*)d_in[3];
  const float* bfc = (const float*)d_in[4];
  const float* W2  = (const float*)d_in[5];
  const float* b2  = (const float*)d_in[6];
  const int* nidx  = (const int*)d_in[7];
  const int* nmask = (const int*)d_in[8];
  float* out = (float*)d_out;

  f16* wsf = (f16*)d_ws;
  f16* w1h = wsf;
  f16* w1l = w1h + 12288;
  f16* wfh = w1l + 12288;
  f16* wfl = wfh + 16384;
  f16* w2h = wfl + 16384;
  f16* w2l = w2h + 24576;
  f16* h16 = w2l + 24576;
  f16* agg16 = h16 + (size_t)NPTS * TDIM * FDIM;
  f16* z16 = agg16 + (size_t)NPTS * TDIM * FDIM;

  prep_kernel<<<96, 256, 0, stream>>>(W1, Wfc, W2, w1h, w1l, wfh, wfl, w2h, w2l);
  conv1_kernel<<<NPTS / NG, 256, 0, stream>>>(x, w1h, w1l, b1, h16);
  gather_kernel<<<(NPTS * TDIM) / 8, 256, 0, stream>>>(h16, nidx, nmask, agg16);
  fc_kernel<<<NPTS / NG, 256, 0, stream>>>(h16, agg16, wfh, wfl, bfc, z16);
  conv2_kernel<<<NPTS / NG, 256, 0, stream>>>(z16, w2h, w2l, b2, out);
}

// Round 5
// 720.298 us; speedup vs baseline: 2.8809x; 1.3238x over previous
//
#include <hip/hip_runtime.h>
#include <cstddef>
#include <cstdint>

#define NPTS 10000
#define TDIM 64
#define CINDIM 64
#define FDIM 64
#define HIDDIM 128
#define SDIM 8
#define NG 4  // n's per block in matmul kernels

typedef _Float16 f16;
typedef _Float16 f16x2 __attribute__((ext_vector_type(2)));
typedef _Float16 f16x4 __attribute__((ext_vector_type(4)));
typedef _Float16 f16x8 __attribute__((ext_vector_type(8)));
typedef float f32x4 __attribute__((ext_vector_type(4)));
typedef float f32x16 __attribute__((ext_vector_type(16)));

#define MFMA32(a, b, c) __builtin_amdgcn_mfma_f32_32x32x16_f16((a), (b), (c), 0, 0, 0)

static __device__ __forceinline__ f16x2 pk(float a, float b) {
  return __builtin_bit_cast(f16x2, __builtin_amdgcn_cvt_pkrtz(a, b));
}
static __device__ __forceinline__ f16x8 pack8(f32x4 p, f32x4 q) {
  f16x2 h0 = pk(p[0], p[1]), h1 = pk(p[2], p[3]);
  f16x2 h2 = pk(q[0], q[1]), h3 = pk(q[2], q[3]);
  f16x4 lo = __builtin_shufflevector(h0, h1, 0, 1, 2, 3);
  f16x4 hi = __builtin_shufflevector(h2, h3, 0, 1, 2, 3);
  return __builtin_shufflevector(lo, hi, 0, 1, 2, 3, 4, 5, 6, 7);
}
static __device__ __forceinline__ f16x4 pack4_relu(f32x4 v, f32x4 bias) {
  f16x4 r;
  r[0] = (f16)fmaxf(v[0] + bias[0], 0.f);
  r[1] = (f16)fmaxf(v[1] + bias[1], 0.f);
  r[2] = (f16)fmaxf(v[2] + bias[2], 0.f);
  r[3] = (f16)fmaxf(v[3] + bias[3], 0.f);
  return r;
}

// ---------------------------------------------------------------------------
// prep: round weights to f16 (single-pass; analog err ~1e-3 << bf16 ulp) and
// pre-shuffle into 32x32x16 A-frag order: lane l holds A[row=l&31]
// [kk_local=(l>>5)*8+j]. Storage [slice][ks][lane][j], kk = ks*16+(l>>5)*8+j.
//   conv1 kk = k*64 + c   (K=192, 12 ks, 2 slices)
//   fc    kk = c          (K=128,  8 ks, 4 slices)
//   conv2 kk = k*128 + c  (K=384, 24 ks, 2 slices)
// ---------------------------------------------------------------------------
__global__ __launch_bounds__(256) void prep_kernel(
    const float* __restrict__ W1, const float* __restrict__ Wfc,
    const float* __restrict__ W2, f16* __restrict__ w1h,
    f16* __restrict__ wfh, f16* __restrict__ w2h) {
  const int idx = blockIdx.x * 256 + threadIdx.x;
  const int j = idx & 7;
  if (idx < 2 * 12 * 512) {  // w1
    const int s = idx / 6144, rem = idx % 6144;
    const int ks = rem / 512, l = (rem % 512) >> 3;
    const int kk = ks * 16 + ((l >> 5) << 3) + j;
    const int k = kk >> 6, c = kk & 63, f = s * 32 + (l & 31);
    w1h[idx] = (f16)W1[f * 192 + c * 3 + k];
  }
  if (idx < 4 * 8 * 512) {  // wfc
    const int s = idx / 4096, rem = idx % 4096;
    const int ks = rem / 512, l = (rem % 512) >> 3;
    const int kk = ks * 16 + ((l >> 5) << 3) + j;
    const int hc = s * 32 + (l & 31);
    wfh[idx] = (f16)Wfc[hc * 128 + kk];
  }
  if (idx < 2 * 24 * 512) {  // w2
    const int s = idx / 12288, rem = idx % 12288;
    const int ks = rem / 512, l = (rem % 512) >> 3;
    const int kk = ks * 16 + ((l >> 5) << 3) + j;
    const int k = kk >> 7, c = kk & 127, f = s * 32 + (l & 31);
    w2h[idx] = (f16)W2[f * 384 + c * 3 + k];
  }
}

// ---------------------------------------------------------------------------
// xcvt: x fp32 -> f16 once (moves conv1's pack VALU into a BW-bound pass).
// ---------------------------------------------------------------------------
__global__ __launch_bounds__(256) void xcvt_kernel(const float* __restrict__ x,
                                                   f16* __restrict__ x16) {
  const size_t base = ((size_t)blockIdx.x * 256 + threadIdx.x) * 8;
  const f32x4 p = *(const f32x4*)&x[base];
  const f32x4 q = *(const f32x4*)&x[base + 4];
  *(f16x8*)&x16[base] = pack8(p, q);
}

// ---------------------------------------------------------------------------
// conv1: h[t-major][n][f] = relu(b1 + sum_{k,c} W1[f,c,k] x16[n, t-4+2k, c])
// Wave w: M-slice s=w>>1 (f in [32s,32s+32)), t-half th=w&1. One 32x32 acc.
// B-frag: lane reads x16[n][r = th*32+(l&31)-4+2k][c0..c0+8), c0=(ks&3)*16+hi*8.
// ---------------------------------------------------------------------------
__global__ __launch_bounds__(256) void conv1_kernel(
    const f16* __restrict__ x16, const f16* __restrict__ w1h,
    const float* __restrict__ b1, f16* __restrict__ h16) {
  const int tid = threadIdx.x;
  const int w = tid >> 6, lane = tid & 63;
  const int s = w >> 1, th = w & 1;
  const int rl = lane & 31, hi = lane >> 5;
  const f16x8 fz = {};
  f16x8 wh[12];
#pragma unroll
  for (int ks = 0; ks < 12; ++ks)
    wh[ks] = *(const f16x8*)&w1h[((s * 12 + ks) * 64 + lane) * 8];
  f32x4 bias[4];
#pragma unroll
  for (int q = 0; q < 4; ++q) bias[q] = *(const f32x4*)&b1[s * 32 + 8 * q + 4 * hi];

  for (int g = 0; g < NG; ++g) {
    const int n = blockIdx.x * NG + g;
    const f16* xn = x16 + (size_t)n * (TDIM * CINDIM);
    f32x16 acc;
#pragma unroll
    for (int i = 0; i < 16; ++i) acc[i] = 0.f;
#pragma unroll
    for (int ks = 0; ks < 12; ++ks) {
      const int k = ks >> 2;
      const int c0 = (ks & 3) * 16 + hi * 8;
      const int r = th * 32 + rl - 4 + 2 * k;
      f16x8 b = (r >= 0) ? *(const f16x8*)&xn[r * 64 + c0] : fz;
      acc = MFMA32(wh[ks], b, acc);
    }
    const int t = th * 32 + rl;
    f16* hrow = h16 + ((size_t)t * NPTS + n) * 64;
#pragma unroll
    for (int q = 0; q < 4; ++q) {
      const f32x4 sub = {acc[4 * q], acc[4 * q + 1], acc[4 * q + 2], acc[4 * q + 3]};
      *(f16x4*)&hrow[s * 32 + 8 * q + 4 * hi] = pack4_relu(sub, bias[q]);
    }
  }
}

// ---------------------------------------------------------------------------
// gather: agg[n][t][:] = masked-mean_s h16[t][idx[t,n,s]][:] (fallback self).
// h16 is t-major: all reads for one t live in a 1.28 MB slab (fits XCD L2).
// Block swizzle: XCD x (= blockIdx&7) handles t in [8x, 8x+8) so each XCD
// streams its slabs through its own L2. Half-wave per (t,n); lane=2 features.
// ---------------------------------------------------------------------------
__global__ __launch_bounds__(256) void gather_kernel(
    const f16* __restrict__ h16, const int* __restrict__ nidx,
    const int* __restrict__ nmask, f16* __restrict__ agg16) {
  const int tid = threadIdx.x;
  const int b = blockIdx.x;
  const int xcd = b & 7, jj = b >> 3;          // jj in [0,10000)
  const int t = xcd * 8 + jj / 1250;           // 8 t's per XCD
  const int n = (jj % 1250) * 8 + (tid >> 5);  // 8 half-wave pairs per block
  const int lane32 = tid & 31;
  const uint32_t* h32 = (const uint32_t*)h16;
  uint32_t* agg32 = (uint32_t*)agg16;
  const size_t base8 = ((size_t)t * NPTS + n) * SDIM;
  float ax = 0.f, ay = 0.f;
  int cnt = 0;
#pragma unroll
  for (int s = 0; s < SDIM; ++s) {
    if (nmask[base8 + s] != 0) {
      const int nb = nidx[base8 + s];
      const uint32_t u = h32[((size_t)t * NPTS + nb) * 32 + lane32];
      const f16x2 hv = *(const f16x2*)&u;
      ax += (float)hv[0];
      ay += (float)hv[1];
      ++cnt;
    }
  }
  f16x2 outv;
  if (cnt > 0) {
    const float inv = 1.f / (float)cnt;
    outv[0] = (f16)(ax * inv);
    outv[1] = (f16)(ay * inv);
  } else {
    const uint32_t u = h32[((size_t)t * NPTS + n) * 32 + lane32];
    outv = *(const f16x2*)&u;
  }
  agg32[((size_t)n * 64 + t) * 32 + lane32] = *(const uint32_t*)&outv;
}

// ---------------------------------------------------------------------------
// fc: z[n][t][hc] = relu(bfc + sum_c [h|agg][n,t,c] Wfc[hc,c]).
// Wave w: M-pair mp=w>>1 (hc slices {2mp,2mp+1}), t-half th=w&1.
// ks<4 read h16 (t-major), ks>=4 read agg16 (n-major).
// ---------------------------------------------------------------------------
__global__ __launch_bounds__(256) void fc_kernel(
    const f16* __restrict__ h16, const f16* __restrict__ agg16,
    const f16* __restrict__ wfh, const float* __restrict__ bfc,
    f16* __restrict__ z16) {
  const int tid = threadIdx.x;
  const int w = tid >> 6, lane = tid & 63;
  const int mp = w >> 1, th = w & 1;
  const int rl = lane & 31, hi = lane >> 5;
  f16x8 whA[8], whB[8];
#pragma unroll
  for (int ks = 0; ks < 8; ++ks) {
    whA[ks] = *(const f16x8*)&wfh[(((2 * mp) * 8 + ks) * 64 + lane) * 8];
    whB[ks] = *(const f16x8*)&wfh[(((2 * mp + 1) * 8 + ks) * 64 + lane) * 8];
  }
  f32x4 biasA[4], biasB[4];
#pragma unroll
  for (int q = 0; q < 4; ++q) {
    biasA[q] = *(const f32x4*)&bfc[(2 * mp) * 32 + 8 * q + 4 * hi];
    biasB[q] = *(const f32x4*)&bfc[(2 * mp + 1) * 32 + 8 * q + 4 * hi];
  }
  const int t = th * 32 + rl;
  for (int g = 0; g < NG; ++g) {
    const int n = blockIdx.x * NG + g;
    f32x16 accA, accB;
#pragma unroll
    for (int i = 0; i < 16; ++i) { accA[i] = 0.f; accB[i] = 0.f; }
    f16x8 bf[8];
#pragma unroll
    for (int ks = 0; ks < 8; ++ks) {
      const int c0 = ks * 16 + hi * 8;
      bf[ks] = (ks < 4)
          ? *(const f16x8*)&h16[((size_t)t * NPTS + n) * 64 + c0]
          : *(const f16x8*)&agg16[((size_t)n * 64 + t) * 64 + (c0 - 64)];
    }
#pragma unroll
    for (int ks = 0; ks < 8; ++ks) accA = MFMA32(whA[ks], bf[ks], accA);
#pragma unroll
    for (int ks = 0; ks < 8; ++ks) accB = MFMA32(whB[ks], bf[ks], accB);
    f16* zrow = z16 + ((size_t)n * 64 + t) * 128;
#pragma unroll
    for (int q = 0; q < 4; ++q) {
      const f32x4 sa = {accA[4 * q], accA[4 * q + 1], accA[4 * q + 2], accA[4 * q + 3]};
      const f32x4 sb = {accB[4 * q], accB[4 * q + 1], accB[4 * q + 2], accB[4 * q + 3]};
      *(f16x4*)&zrow[(2 * mp) * 32 + 8 * q + 4 * hi] = pack4_relu(sa, biasA[q]);
      *(f16x4*)&zrow[(2 * mp + 1) * 32 + 8 * q + 4 * hi] = pack4_relu(sb, biasB[q]);
    }
  }
}

// ---------------------------------------------------------------------------
// conv2: out[n,t,f] = relu(b2 + sum_{k,c} W2[f,c,k] z[n, t-4+2k, c]). fp32 out.
// Wave w: M-slice s=w>>1, t-half th=w&1. 24 ks; weights 96 VGPR.
// ---------------------------------------------------------------------------
__global__ __launch_bounds__(256) void conv2_kernel(
    const f16* __restrict__ z16, const f16* __restrict__ w2h,
    const float* __restrict__ b2, float* __restrict__ out) {
  const int tid = threadIdx.x;
  const int w = tid >> 6, lane = tid & 63;
  const int s = w >> 1, th = w & 1;
  const int rl = lane & 31, hi = lane >> 5;
  const f16x8 fz = {};
  f16x8 wh[24];
#pragma unroll
  for (int ks = 0; ks < 24; ++ks)
    wh[ks] = *(const f16x8*)&w2h[((s * 24 + ks) * 64 + lane) * 8];
  f32x4 bias[4];
#pragma unroll
  for (int q = 0; q < 4; ++q) bias[q] = *(const f32x4*)&b2[s * 32 + 8 * q + 4 * hi];

  for (int g = 0; g < NG; ++g) {
    const int n = blockIdx.x * NG + g;
    const f16* zn = z16 + (size_t)n * (TDIM * HIDDIM);
    f32x16 acc;
#pragma unroll
    for (int i = 0; i < 16; ++i) acc[i] = 0.f;
#pragma unroll
    for (int ks = 0; ks < 24; ++ks) {
      const int k = ks >> 3;
      const int c0 = (ks & 7) * 16 + hi * 8;
      const int r = th * 32 + rl - 4 + 2 * k;
      f16x8 b = (r >= 0) ? *(const f16x8*)&zn[r * 128 + c0] : fz;
      acc = MFMA32(wh[ks], b, acc);
    }
    const int t = th * 32 + rl;
    float* orow = out + ((size_t)n * 64 + t) * 64;
#pragma unroll
    for (int q = 0; q < 4; ++q) {
      f32x4 v;
      v[0] = fmaxf(acc[4 * q + 0] + bias[q][0], 0.f);
      v[1] = fmaxf(acc[4 * q + 1] + bias[q][1], 0.f);
      v[2] = fmaxf(acc[4 * q + 2] + bias[q][2], 0.f);
      v[3] = fmaxf(acc[4 * q + 3] + bias[q][3], 0.f);
      *(f32x4*)&orow[s * 32 + 8 * q + 4 * hi] = v;
    }
  }
}

// ---------------------------------------------------------------------------
// Workspace (f16 units): w1h 12288 | wfh 16384 | w2h 24576 |
//   x16 41M | h16 41M (t-major) | agg16 41M | z16 82M  -> ~410 MB total.
// ---------------------------------------------------------------------------
extern "C" void kernel_launch(void* const* d_in, const int* in_sizes, int n_in,
                              void* d_out, int out_size, void* d_ws, size_t ws_size,
                              hipStream_t stream) {
  (void)in_sizes; (void)n_in; (void)out_size; (void)ws_size;
  const float* x   = (const float*)d_in[0];
  const float* W1  = (const float*)d_in[1];
  const float* b1  = (const float*)d_in[2];
  const float* Wfc = (const float*)d_in[3];
  const float* bfc = (const float*)d_in[4];
  const float* W2  = (const float*)d_in[5];
  const float* b2  = (const float*)d_in[6];
  const int* nidx  = (const int*)d_in[7];
  const int* nmask = (const int*)d_in[8];
  float* out = (float*)d_out;

  f16* wsf = (f16*)d_ws;
  f16* w1h = wsf;
  f16* wfh = w1h + 12288;
  f16* w2h = wfh + 16384;
  f16* x16 = w2h + 24576;
  f16* h16 = x16 + (size_t)NPTS * TDIM * CINDIM;
  f16* agg16 = h16 + (size_t)NPTS * TDIM * FDIM;
  f16* z16 = agg16 + (size_t)NPTS * TDIM * FDIM;

  prep_kernel<<<96, 256, 0, stream>>>(W1, Wfc, W2, w1h, wfh, w2h);
  xcvt_kernel<<<(NPTS * TDIM * CINDIM) / (256 * 8), 256, 0, stream>>>(x, x16);
  conv1_kernel<<<NPTS / NG, 256, 0, stream>>>(x16, w1h, b1, h16);
  gather_kernel<<<NPTS * 8, 256, 0, stream>>>(h16, nidx, nmask, agg16);
  fc_kernel<<<NPTS / NG, 256, 0, stream>>>(h16, agg16, wfh, bfc, z16);
  conv2_kernel<<<NPTS / NG, 256, 0, stream>>>(z16, w2h, b2, out);
}

// Round 6
// 617.762 us; speedup vs baseline: 3.3590x; 1.1660x over previous
//
#include <hip/hip_runtime.h>
#include <cstddef>
#include <cstdint>

#define NPTS 10000
#define TDIM 64
#define CINDIM 64
#define FDIM 64
#define HIDDIM 128
#define SDIM 8
#define NG 4     // n's per block in matmul kernels
#define GNB 2000 // gather blocks
#define GNIT 40  // gather iterations per block

typedef _Float16 f16;
typedef _Float16 f16x2 __attribute__((ext_vector_type(2)));
typedef _Float16 f16x4 __attribute__((ext_vector_type(4)));
typedef _Float16 f16x8 __attribute__((ext_vector_type(8)));
typedef float f32x4 __attribute__((ext_vector_type(4)));
typedef float f32x16 __attribute__((ext_vector_type(16)));

#define MFMA32(a, b, c) __builtin_amdgcn_mfma_f32_32x32x16_f16((a), (b), (c), 0, 0, 0)

static __device__ __forceinline__ f16x2 pk(float a, float b) {
  return __builtin_bit_cast(f16x2, __builtin_amdgcn_cvt_pkrtz(a, b));
}
static __device__ __forceinline__ f16x8 pack8(f32x4 p, f32x4 q) {
  f16x2 h0 = pk(p[0], p[1]), h1 = pk(p[2], p[3]);
  f16x2 h2 = pk(q[0], q[1]), h3 = pk(q[2], q[3]);
  f16x4 lo = __builtin_shufflevector(h0, h1, 0, 1, 2, 3);
  f16x4 hi = __builtin_shufflevector(h2, h3, 0, 1, 2, 3);
  return __builtin_shufflevector(lo, hi, 0, 1, 2, 3, 4, 5, 6, 7);
}
static __device__ __forceinline__ f16x4 pack4_relu(f32x4 v, f32x4 bias) {
  f16x4 r;
  r[0] = (f16)fmaxf(v[0] + bias[0], 0.f);
  r[1] = (f16)fmaxf(v[1] + bias[1], 0.f);
  r[2] = (f16)fmaxf(v[2] + bias[2], 0.f);
  r[3] = (f16)fmaxf(v[3] + bias[3], 0.f);
  return r;
}

// ---------------------------------------------------------------------------
// prep: round weights to f16 and pre-shuffle into 32x32x16 A-frag order:
// lane l holds A[row=l&31][kk=(l>>5)*8+j]. Storage [slice][ks][lane][j],
// kk = ks*16+(l>>5)*8+j.
//   conv1 kk = k*64 + c   (K=192, 12 ks, 2 slices)
//   fc    kk = c          (K=128,  8 ks, 4 slices)
//   conv2 kk = k*128 + c  (K=384, 24 ks, 2 slices)
// ---------------------------------------------------------------------------
__global__ __launch_bounds__(256) void prep_kernel(
    const float* __restrict__ W1, const float* __restrict__ Wfc,
    const float* __restrict__ W2, f16* __restrict__ w1h,
    f16* __restrict__ wfh, f16* __restrict__ w2h) {
  const int idx = blockIdx.x * 256 + threadIdx.x;
  const int j = idx & 7;
  if (idx < 2 * 12 * 512) {  // w1
    const int s = idx / 6144, rem = idx % 6144;
    const int ks = rem / 512, l = (rem % 512) >> 3;
    const int kk = ks * 16 + ((l >> 5) << 3) + j;
    const int k = kk >> 6, c = kk & 63, f = s * 32 + (l & 31);
    w1h[idx] = (f16)W1[f * 192 + c * 3 + k];
  }
  if (idx < 4 * 8 * 512) {  // wfc
    const int s = idx / 4096, rem = idx % 4096;
    const int ks = rem / 512, l = (rem % 512) >> 3;
    const int kk = ks * 16 + ((l >> 5) << 3) + j;
    const int hc = s * 32 + (l & 31);
    wfh[idx] = (f16)Wfc[hc * 128 + kk];
  }
  if (idx < 2 * 24 * 512) {  // w2
    const int s = idx / 12288, rem = idx % 12288;
    const int ks = rem / 512, l = (rem % 512) >> 3;
    const int kk = ks * 16 + ((l >> 5) << 3) + j;
    const int k = kk >> 7, c = kk & 127, f = s * 32 + (l & 31);
    w2h[idx] = (f16)W2[f * 384 + c * 3 + k];
  }
}

// ---------------------------------------------------------------------------
// conv1: relu(b1 + sum_{k,c} W1[f,c,k] x[n, t-4+2k, c]); writes h in BOTH
// n-major (h16, for fc) and t-major (h16t, for gather's L2-local random reads).
// Wave w: M-slice s=w>>1 (f in [32s,32s+32)), t-half th=w&1.
// ---------------------------------------------------------------------------
__global__ __launch_bounds__(256) void conv1_kernel(
    const float* __restrict__ x, const f16* __restrict__ w1h,
    const float* __restrict__ b1, f16* __restrict__ h16,
    f16* __restrict__ h16t) {
  const int tid = threadIdx.x;
  const int w = tid >> 6, lane = tid & 63;
  const int s = w >> 1, th = w & 1;
  const int rl = lane & 31, hi = lane >> 5;
  const f16x8 fz = {};
  f16x8 wh[12];
#pragma unroll
  for (int ks = 0; ks < 12; ++ks)
    wh[ks] = *(const f16x8*)&w1h[((s * 12 + ks) * 64 + lane) * 8];
  f32x4 bias[4];
#pragma unroll
  for (int q = 0; q < 4; ++q) bias[q] = *(const f32x4*)&b1[s * 32 + 8 * q + 4 * hi];

  for (int g = 0; g < NG; ++g) {
    const int n = blockIdx.x * NG + g;
    const float* xn = x + (size_t)n * (TDIM * CINDIM);
    f32x16 acc;
#pragma unroll
    for (int i = 0; i < 16; ++i) acc[i] = 0.f;
#pragma unroll
    for (int ks = 0; ks < 12; ++ks) {
      const int k = ks >> 2;
      const int c0 = (ks & 3) * 16 + hi * 8;
      const int r = th * 32 + rl - 4 + 2 * k;
      f16x8 b = fz;
      if (r >= 0) {
        const f32x4 p = *(const f32x4*)&xn[r * 64 + c0];
        const f32x4 q = *(const f32x4*)&xn[r * 64 + c0 + 4];
        b = pack8(p, q);
      }
      acc = MFMA32(wh[ks], b, acc);
    }
    const int t = th * 32 + rl;
    f16* hrow = h16 + ((size_t)n * 64 + t) * 64;
    f16* hrowt = h16t + ((size_t)t * NPTS + n) * 64;
#pragma unroll
    for (int q = 0; q < 4; ++q) {
      const f32x4 sub = {acc[4 * q], acc[4 * q + 1], acc[4 * q + 2], acc[4 * q + 3]};
      const f16x4 v = pack4_relu(sub, bias[q]);
      *(f16x4*)&hrow[s * 32 + 8 * q + 4 * hi] = v;
      *(f16x4*)&hrowt[s * 32 + 8 * q + 4 * hi] = v;
    }
  }
}

// ---------------------------------------------------------------------------
// gather: agg[n][t][:] = masked-mean_s h16t[t][idx[t,n,s]][:] (fallback self).
// Grid-stride, latency-pipelined: 2000 blocks x 40 iters; half-wave owns one
// (t,n) pair per iter. idx/mask prefetched one iter ahead (4x int4). Gather
// loads unconditional (mask applied as 0/1 multiplier -> no divergence, all 8
// loads in flight). Pair order p = xcd*80000 + j*2000 + q*8 + hw keeps each
// XCD's concurrent window inside one ~1.3 MB t-slab (fits its private L2).
// ---------------------------------------------------------------------------
__global__ __launch_bounds__(256) void gather_kernel(
    const f16* __restrict__ h16t, const int* __restrict__ nidx,
    const int* __restrict__ nmask, f16* __restrict__ agg16) {
  const int tid = threadIdx.x;
  const int hw = tid >> 5, lane32 = tid & 31;
  const int xcd = blockIdx.x & 7, q = blockIdx.x >> 3;
  const uint32_t* h32 = (const uint32_t*)h16t;
  uint32_t* agg32 = (uint32_t*)agg16;

  int p = xcd * 80000 + q * 8 + hw;
  int4 ci0 = *(const int4*)&nidx[(size_t)p * 8];
  int4 ci1 = *(const int4*)&nidx[(size_t)p * 8 + 4];
  int4 cm0 = *(const int4*)&nmask[(size_t)p * 8];
  int4 cm1 = *(const int4*)&nmask[(size_t)p * 8 + 4];

  for (int j = 0; j < GNIT; ++j) {
    const int pn = p + GNB;
    int4 ni0 = {0, 0, 0, 0}, ni1 = {0, 0, 0, 0};
    int4 nm0 = {0, 0, 0, 0}, nm1 = {0, 0, 0, 0};
    if (j + 1 < GNIT) {  // prefetch next pair's idx/mask
      ni0 = *(const int4*)&nidx[(size_t)pn * 8];
      ni1 = *(const int4*)&nidx[(size_t)pn * 8 + 4];
      nm0 = *(const int4*)&nmask[(size_t)pn * 8];
      nm1 = *(const int4*)&nmask[(size_t)pn * 8 + 4];
    }
    const int t = p / 10000;
    const int n = p - t * 10000;
    const size_t trow = (size_t)t * NPTS;
    const int idx8[8] = {ci0.x, ci0.y, ci0.z, ci0.w, ci1.x, ci1.y, ci1.z, ci1.w};
    const int msk8[8] = {cm0.x, cm0.y, cm0.z, cm0.w, cm1.x, cm1.y, cm1.z, cm1.w};
    uint32_t u[8];
#pragma unroll
    for (int s = 0; s < SDIM; ++s)
      u[s] = h32[(trow + idx8[s]) * 32 + lane32];
    float ax = 0.f, ay = 0.f, cnt = 0.f;
#pragma unroll
    for (int s = 0; s < SDIM; ++s) {
      const float m = (msk8[s] != 0) ? 1.f : 0.f;
      const f16x2 hv = __builtin_bit_cast(f16x2, u[s]);
      ax = fmaf(m, (float)hv[0], ax);
      ay = fmaf(m, (float)hv[1], ay);
      cnt += m;
    }
    f16x2 outv;
    if (cnt > 0.f) {
      const float inv = 1.f / cnt;
      outv[0] = (f16)(ax * inv);
      outv[1] = (f16)(ay * inv);
    } else {
      const uint32_t su = h32[(trow + n) * 32 + lane32];
      outv = __builtin_bit_cast(f16x2, su);
    }
    agg32[((size_t)n * 64 + t) * 32 + lane32] = __builtin_bit_cast(uint32_t, outv);
    ci0 = ni0; ci1 = ni1; cm0 = nm0; cm1 = nm1;
    p = pn;
  }
}

// ---------------------------------------------------------------------------
// fc: z[n][t][hc] = relu(bfc + sum_c [h|agg][n,t,c] Wfc[hc,c]).
// Wave w: M-pair mp=w>>1 (hc slices {2mp,2mp+1}), t-half th=w&1.
// Both h16 and agg16 read n-major (8 KB/n window -> L1-resident).
// ---------------------------------------------------------------------------
__global__ __launch_bounds__(256) void fc_kernel(
    const f16* __restrict__ h16, const f16* __restrict__ agg16,
    const f16* __restrict__ wfh, const float* __restrict__ bfc,
    f16* __restrict__ z16) {
  const int tid = threadIdx.x;
  const int w = tid >> 6, lane = tid & 63;
  const int mp = w >> 1, th = w & 1;
  const int rl = lane & 31, hi = lane >> 5;
  f16x8 whA[8], whB[8];
#pragma unroll
  for (int ks = 0; ks < 8; ++ks) {
    whA[ks] = *(const f16x8*)&wfh[(((2 * mp) * 8 + ks) * 64 + lane) * 8];
    whB[ks] = *(const f16x8*)&wfh[(((2 * mp + 1) * 8 + ks) * 64 + lane) * 8];
  }
  f32x4 biasA[4], biasB[4];
#pragma unroll
  for (int q = 0; q < 4; ++q) {
    biasA[q] = *(const f32x4*)&bfc[(2 * mp) * 32 + 8 * q + 4 * hi];
    biasB[q] = *(const f32x4*)&bfc[(2 * mp + 1) * 32 + 8 * q + 4 * hi];
  }
  const int t = th * 32 + rl;
  for (int g = 0; g < NG; ++g) {
    const int n = blockIdx.x * NG + g;
    f32x16 accA, accB;
#pragma unroll
    for (int i = 0; i < 16; ++i) { accA[i] = 0.f; accB[i] = 0.f; }
    f16x8 bf[8];
#pragma unroll
    for (int ks = 0; ks < 8; ++ks) {
      const int c0 = ks * 16 + hi * 8;
      bf[ks] = (ks < 4)
          ? *(const f16x8*)&h16[((size_t)n * 64 + t) * 64 + c0]
          : *(const f16x8*)&agg16[((size_t)n * 64 + t) * 64 + (c0 - 64)];
    }
#pragma unroll
    for (int ks = 0; ks < 8; ++ks) accA = MFMA32(whA[ks], bf[ks], accA);
#pragma unroll
    for (int ks = 0; ks < 8; ++ks) accB = MFMA32(whB[ks], bf[ks], accB);
    f16* zrow = z16 + ((size_t)n * 64 + t) * 128;
#pragma unroll
    for (int q = 0; q < 4; ++q) {
      const f32x4 sa = {accA[4 * q], accA[4 * q + 1], accA[4 * q + 2], accA[4 * q + 3]};
      const f32x4 sb = {accB[4 * q], accB[4 * q + 1], accB[4 * q + 2], accB[4 * q + 3]};
      *(f16x4*)&zrow[(2 * mp) * 32 + 8 * q + 4 * hi] = pack4_relu(sa, biasA[q]);
      *(f16x4*)&zrow[(2 * mp + 1) * 32 + 8 * q + 4 * hi] = pack4_relu(sb, biasB[q]);
    }
  }
}

// ---------------------------------------------------------------------------
// conv2: out[n,t,f] = relu(b2 + sum_{k,c} W2[f,c,k] z[n, t-4+2k, c]). fp32 out.
// Wave w: M-slice s=w>>1, t-half th=w&1. 24 ks; weights 96 VGPR.
// ---------------------------------------------------------------------------
__global__ __launch_bounds__(256) void conv2_kernel(
    const f16* __restrict__ z16, const f16* __restrict__ w2h,
    const float* __restrict__ b2, float* __restrict__ out) {
  const int tid = threadIdx.x;
  const int w = tid >> 6, lane = tid & 63;
  const int s = w >> 1, th = w & 1;
  const int rl = lane & 31, hi = lane >> 5;
  const f16x8 fz = {};
  f16x8 wh[24];
#pragma unroll
  for (int ks = 0; ks < 24; ++ks)
    wh[ks] = *(const f16x8*)&w2h[((s * 24 + ks) * 64 + lane) * 8];
  f32x4 bias[4];
#pragma unroll
  for (int q = 0; q < 4; ++q) bias[q] = *(const f32x4*)&b2[s * 32 + 8 * q + 4 * hi];

  for (int g = 0; g < NG; ++g) {
    const int n = blockIdx.x * NG + g;
    const f16* zn = z16 + (size_t)n * (TDIM * HIDDIM);
    f32x16 acc;
#pragma unroll
    for (int i = 0; i < 16; ++i) acc[i] = 0.f;
#pragma unroll
    for (int ks = 0; ks < 24; ++ks) {
      const int k = ks >> 3;
      const int c0 = (ks & 7) * 16 + hi * 8;
      const int r = th * 32 + rl - 4 + 2 * k;
      f16x8 b = (r >= 0) ? *(const f16x8*)&zn[r * 128 + c0] : fz;
      acc = MFMA32(wh[ks], b, acc);
    }
    const int t = th * 32 + rl;
    float* orow = out + ((size_t)n * 64 + t) * 64;
#pragma unroll
    for (int q = 0; q < 4; ++q) {
      f32x4 v;
      v[0] = fmaxf(acc[4 * q + 0] + bias[q][0], 0.f);
      v[1] = fmaxf(acc[4 * q + 1] + bias[q][1], 0.f);
      v[2] = fmaxf(acc[4 * q + 2] + bias[q][2], 0.f);
      v[3] = fmaxf(acc[4 * q + 3] + bias[q][3], 0.f);
      *(f32x4*)&orow[s * 32 + 8 * q + 4 * hi] = v;
    }
  }
}

// ---------------------------------------------------------------------------
// Workspace (f16 units): w1h 12288 | wfh 16384 | w2h 24576 |
//   h16 41M (n-major) | h16t 41M (t-major) | agg16 41M | z16 82M  ~410 MB.
// ---------------------------------------------------------------------------
extern "C" void kernel_launch(void* const* d_in, const int* in_sizes, int n_in,
                              void* d_out, int out_size, void* d_ws, size_t ws_size,
                              hipStream_t stream) {
  (void)in_sizes; (void)n_in; (void)out_size; (void)ws_size;
  const float* x   = (const float*)d_in[0];
  const float* W1  = (const float*)d_in[1];
  const float* b1  = (const float*)d_in[2];
  const float* Wfc = (const float*)d_in[3];
  const float* bfc = (const float*)d_in[4];
  const float* W2  = (const float*)d_in[5];
  const float* b2  = (const float*)d_in[6];
  const int* nidx  = (const int*)d_in[7];
  const int* nmask = (const int*)d_in[8];
  float* out = (float*)d_out;

  f16* wsf = (f16*)d_ws;
  f16* w1h = wsf;
  f16* wfh = w1h + 12288;
  f16* w2h = wfh + 16384;
  f16* h16 = w2h + 24576;
  f16* h16t = h16 + (size_t)NPTS * TDIM * FDIM;
  f16* agg16 = h16t + (size_t)NPTS * TDIM * FDIM;
  f16* z16 = agg16 + (size_t)NPTS * TDIM * FDIM;

  prep_kernel<<<96, 256, 0, stream>>>(W1, Wfc, W2, w1h, wfh, w2h);
  conv1_kernel<<<NPTS / NG, 256, 0, stream>>>(x, w1h, b1, h16, h16t);
  gather_kernel<<<GNB, 256, 0, stream>>>(h16t, nidx, nmask, agg16);
  fc_kernel<<<NPTS / NG, 256, 0, stream>>>(h16, agg16, wfh, bfc, z16);
  conv2_kernel<<<NPTS / NG, 256, 0, stream>>>(z16, w2h, b2, out);
}

// Round 9
// 349.096 us; speedup vs baseline: 5.9441x; 1.7696x over previous
//
#include <hip/hip_runtime.h>
#include <cstddef>
#include <cstdint>

#define NPTS 10000
#define TDIM 64
#define CINDIM 64
#define FDIM 64
#define HIDDIM 128
#define SDIM 8
#define NG 4     // n's per block in matmul kernels
#define GNB 2000 // gather blocks
#define GNIT 40  // gather iterations per block

typedef _Float16 f16;
typedef _Float16 f16x2 __attribute__((ext_vector_type(2)));
typedef _Float16 f16x4 __attribute__((ext_vector_type(4)));
typedef _Float16 f16x8 __attribute__((ext_vector_type(8)));
typedef float f32x4 __attribute__((ext_vector_type(4)));
typedef float f32x16 __attribute__((ext_vector_type(16)));

#define MFMA32(a, b, c) __builtin_amdgcn_mfma_f32_32x32x16_f16((a), (b), (c), 0, 0, 0)

static __device__ __forceinline__ f16x2 pk(float a, float b) {
  return __builtin_bit_cast(f16x2, __builtin_amdgcn_cvt_pkrtz(a, b));
}
static __device__ __forceinline__ f16x4 pack4(f32x4 p) {
  f16x2 h0 = pk(p[0], p[1]), h1 = pk(p[2], p[3]);
  return __builtin_shufflevector(h0, h1, 0, 1, 2, 3);
}
static __device__ __forceinline__ f16x4 pack4_relu(f32x4 v, f32x4 bias) {
  f16x4 r;
  r[0] = (f16)fmaxf(v[0] + bias[0], 0.f);
  r[1] = (f16)fmaxf(v[1] + bias[1], 0.f);
  r[2] = (f16)fmaxf(v[2] + bias[2], 0.f);
  r[3] = (f16)fmaxf(v[3] + bias[3], 0.f);
  return r;
}

// ---------------------------------------------------------------------------
// prep: round weights to f16 and pre-shuffle into 32x32x16 A-frag order:
// lane l holds A[row=l&31][kk=(l>>5)*8+j]. Storage [slice][ks][lane][j],
// kk = ks*16+(l>>5)*8+j.
//   conv1 kk = k*64 + c   (K=192, 12 ks, 2 slices)
//   fc    kk = c          (K=128,  8 ks, 4 slices)
//   conv2 kk = k*128 + c  (K=384, 24 ks, 2 slices)
// ---------------------------------------------------------------------------
__global__ __launch_bounds__(256) void prep_kernel(
    const float* __restrict__ W1, const float* __restrict__ Wfc,
    const float* __restrict__ W2, f16* __restrict__ w1h,
    f16* __restrict__ wfh, f16* __restrict__ w2h) {
  const int idx = blockIdx.x * 256 + threadIdx.x;
  const int j = idx & 7;
  if (idx < 2 * 12 * 512) {  // w1
    const int s = idx / 6144, rem = idx % 6144;
    const int ks = rem / 512, l = (rem % 512) >> 3;
    const int kk = ks * 16 + ((l >> 5) << 3) + j;
    const int k = kk >> 6, c = kk & 63, f = s * 32 + (l & 31);
    w1h[idx] = (f16)W1[f * 192 + c * 3 + k];
  }
  if (idx < 4 * 8 * 512) {  // wfc
    const int s = idx / 4096, rem = idx % 4096;
    const int ks = rem / 512, l = (rem % 512) >> 3;
    const int kk = ks * 16 + ((l >> 5) << 3) + j;
    const int hc = s * 32 + (l & 31);
    wfh[idx] = (f16)Wfc[hc * 128 + kk];
  }
  if (idx < 2 * 24 * 512) {  // w2
    const int s = idx / 12288, rem = idx % 12288;
    const int ks = rem / 512, l = (rem % 512) >> 3;
    const int kk = ks * 16 + ((l >> 5) << 3) + j;
    const int k = kk >> 7, c = kk & 127, f = s * 32 + (l & 31);
    w2h[idx] = (f16)W2[f * 384 + c * 3 + k];
  }
}

// ---------------------------------------------------------------------------
// conv1: relu(b1 + sum_{k,c} W1[f,c,k] x[n, t-4+2k, c]).
// LDS-staged: x[n] tile (64x64 fp32) loaded coalesced (16 thr/row, 16B/thr),
// packed to f16 into xs[68][72] (rows 0-3 = causal zero pad; +8 f16 row pad).
// Wave w: M-slice s=w>>1 (f in [32s,32s+32)), t-half th=w&1.
// Writes h in n-major (h16, for fc) and t-major (h16t, for gather).
// ---------------------------------------------------------------------------
__global__ __launch_bounds__(256) void conv1_kernel(
    const float* __restrict__ x, const f16* __restrict__ w1h,
    const float* __restrict__ b1, f16* __restrict__ h16,
    f16* __restrict__ h16t) {
  __shared__ f16 xs[68 * 72];
  const int tid = threadIdx.x;
  const int w = tid >> 6, lane = tid & 63;
  const int s = w >> 1, th = w & 1;
  const int rl = lane & 31, hi = lane >> 5;
  f16x8 wh[12];
#pragma unroll
  for (int ks = 0; ks < 12; ++ks)
    wh[ks] = *(const f16x8*)&w1h[((s * 12 + ks) * 64 + lane) * 8];
  f32x4 bias[4];
#pragma unroll
  for (int q = 0; q < 4; ++q) bias[q] = *(const f32x4*)&b1[s * 32 + 8 * q + 4 * hi];
  // rows 0-3 (causal pad) = 288 f16 = 144 f16x2; 144 <= 256 threads -> full.
  if (tid < 144) ((f16x2*)xs)[tid] = (f16x2){(f16)0, (f16)0};

  for (int g = 0; g < NG; ++g) {
    const int n = blockIdx.x * NG + g;
    const float* xn = x + (size_t)n * (TDIM * CINDIM);
    if (g) __syncthreads();  // previous compute done before overwrite
#pragma unroll
    for (int pass = 0; pass < 4; ++pass) {  // 64 rows x 16 chunks of 4 fp32
      const int idx = pass * 256 + tid;
      const int row = idx >> 4, c4 = (idx & 15) * 4;
      const f32x4 v = *(const f32x4*)&xn[row * 64 + c4];
      *(f16x4*)&xs[(row + 4) * 72 + c4] = pack4(v);
    }
    __syncthreads();

    f32x16 acc;
#pragma unroll
    for (int i = 0; i < 16; ++i) acc[i] = 0.f;
#pragma unroll
    for (int ks = 0; ks < 12; ++ks) {
      const int k = ks >> 2;
      const int c0 = (ks & 3) * 16 + hi * 8;
      const f16x8 b = *(const f16x8*)&xs[(th * 32 + rl + 2 * k) * 72 + c0];
      acc = MFMA32(wh[ks], b, acc);
    }
    const int t = th * 32 + rl;
    f16* hrow = h16 + ((size_t)n * 64 + t) * 64;
    f16* hrowt = h16t + ((size_t)t * NPTS + n) * 64;
#pragma unroll
    for (int q = 0; q < 4; ++q) {
      const f32x4 sub = {acc[4 * q], acc[4 * q + 1], acc[4 * q + 2], acc[4 * q + 3]};
      const f16x4 v = pack4_relu(sub, bias[q]);
      *(f16x4*)&hrow[s * 32 + 8 * q + 4 * hi] = v;
      *(f16x4*)&hrowt[s * 32 + 8 * q + 4 * hi] = v;
    }
  }
}

// ---------------------------------------------------------------------------
// gather: agg[n][t][:] = masked-mean_s h16t[t][idx[t,n,s]][:] (fallback self).
// Grid-stride, latency-pipelined: 2000 blocks x 40 iters; half-wave owns one
// (t,n) pair per iter; idx/mask prefetched one iter ahead; gather loads
// unconditional (mask as 0/1 multiplier). XCD-affine pair order keeps each
// XCD's window inside one ~1.3 MB t-slab (its private L2).
// ---------------------------------------------------------------------------
__global__ __launch_bounds__(256) void gather_kernel(
    const f16* __restrict__ h16t, const int* __restrict__ nidx,
    const int* __restrict__ nmask, f16* __restrict__ agg16) {
  const int tid = threadIdx.x;
  const int hw = tid >> 5, lane32 = tid & 31;
  const int xcd = blockIdx.x & 7, q = blockIdx.x >> 3;
  const uint32_t* h32 = (const uint32_t*)h16t;
  uint32_t* agg32 = (uint32_t*)agg16;

  int p = xcd * 80000 + q * 8 + hw;
  int4 ci0 = *(const int4*)&nidx[(size_t)p * 8];
  int4 ci1 = *(const int4*)&nidx[(size_t)p * 8 + 4];
  int4 cm0 = *(const int4*)&nmask[(size_t)p * 8];
  int4 cm1 = *(const int4*)&nmask[(size_t)p * 8 + 4];

  for (int j = 0; j < GNIT; ++j) {
    const int pn = p + GNB;
    int4 ni0 = {0, 0, 0, 0}, ni1 = {0, 0, 0, 0};
    int4 nm0 = {0, 0, 0, 0}, nm1 = {0, 0, 0, 0};
    if (j + 1 < GNIT) {  // prefetch next pair's idx/mask
      ni0 = *(const int4*)&nidx[(size_t)pn * 8];
      ni1 = *(const int4*)&nidx[(size_t)pn * 8 + 4];
      nm0 = *(const int4*)&nmask[(size_t)pn * 8];
      nm1 = *(const int4*)&nmask[(size_t)pn * 8 + 4];
    }
    const int t = p / 10000;
    const int n = p - t * 10000;
    const size_t trow = (size_t)t * NPTS;
    const int idx8[8] = {ci0.x, ci0.y, ci0.z, ci0.w, ci1.x, ci1.y, ci1.z, ci1.w};
    const int msk8[8] = {cm0.x, cm0.y, cm0.z, cm0.w, cm1.x, cm1.y, cm1.z, cm1.w};
    uint32_t u[8];
#pragma unroll
    for (int s = 0; s < SDIM; ++s)
      u[s] = h32[(trow + idx8[s]) * 32 + lane32];
    float ax = 0.f, ay = 0.f, cnt = 0.f;
#pragma unroll
    for (int s = 0; s < SDIM; ++s) {
      const float m = (msk8[s] != 0) ? 1.f : 0.f;
      const f16x2 hv = __builtin_bit_cast(f16x2, u[s]);
      ax = fmaf(m, (float)hv[0], ax);
      ay = fmaf(m, (float)hv[1], ay);
      cnt += m;
    }
    f16x2 outv;
    if (cnt > 0.f) {
      const float inv = 1.f / cnt;
      outv[0] = (f16)(ax * inv);
      outv[1] = (f16)(ay * inv);
    } else {
      const uint32_t su = h32[(trow + n) * 32 + lane32];
      outv = __builtin_bit_cast(f16x2, su);
    }
    agg32[((size_t)n * 64 + t) * 32 + lane32] = __builtin_bit_cast(uint32_t, outv);
    ci0 = ni0; ci1 = ni1; cm0 = nm0; cm1 = nm1;
    p = pn;
  }
}

// ---------------------------------------------------------------------------
// fc: z[n][t][hc] = relu(bfc + sum_c [h|agg][n,t,c] Wfc[hc,c]).
// LDS-staged: hs/as tiles (64x64 f16 each, +8 pad). Wave w: M-pair mp=w>>1
// (hc slices {2mp,2mp+1}), t-half th=w&1.
// ---------------------------------------------------------------------------
__global__ __launch_bounds__(256) void fc_kernel(
    const f16* __restrict__ h16, const f16* __restrict__ agg16,
    const f16* __restrict__ wfh, const float* __restrict__ bfc,
    f16* __restrict__ z16) {
  __shared__ f16 hs[64 * 72];
  __shared__ f16 as2[64 * 72];
  const int tid = threadIdx.x;
  const int w = tid >> 6, lane = tid & 63;
  const int mp = w >> 1, th = w & 1;
  const int rl = lane & 31, hi = lane >> 5;
  f16x8 whA[8], whB[8];
#pragma unroll
  for (int ks = 0; ks < 8; ++ks) {
    whA[ks] = *(const f16x8*)&wfh[(((2 * mp) * 8 + ks) * 64 + lane) * 8];
    whB[ks] = *(const f16x8*)&wfh[(((2 * mp + 1) * 8 + ks) * 64 + lane) * 8];
  }
  f32x4 biasA[4], biasB[4];
#pragma unroll
  for (int q = 0; q < 4; ++q) {
    biasA[q] = *(const f32x4*)&bfc[(2 * mp) * 32 + 8 * q + 4 * hi];
    biasB[q] = *(const f32x4*)&bfc[(2 * mp + 1) * 32 + 8 * q + 4 * hi];
  }
  const int t = th * 32 + rl;
  for (int g = 0; g < NG; ++g) {
    const int n = blockIdx.x * NG + g;
    if (g) __syncthreads();
#pragma unroll
    for (int pass = 0; pass < 2; ++pass) {  // 64 rows x 8 chunks of 8 f16
      const int idx = pass * 256 + tid;
      const int row = idx >> 3, c8 = (idx & 7) * 8;
      *(f16x8*)&hs[row * 72 + c8] =
          *(const f16x8*)&h16[((size_t)n * 64 + row) * 64 + c8];
      *(f16x8*)&as2[row * 72 + c8] =
          *(const f16x8*)&agg16[((size_t)n * 64 + row) * 64 + c8];
    }
    __syncthreads();

    f32x16 accA, accB;
#pragma unroll
    for (int i = 0; i < 16; ++i) { accA[i] = 0.f; accB[i] = 0.f; }
    f16x8 bf[8];
#pragma unroll
    for (int ks = 0; ks < 8; ++ks) {
      const int c0 = (ks & 3) * 16 + hi * 8;
      bf[ks] = (ks < 4) ? *(const f16x8*)&hs[t * 72 + c0]
                        : *(const f16x8*)&as2[t * 72 + c0];
    }
#pragma unroll
    for (int ks = 0; ks < 8; ++ks) accA = MFMA32(whA[ks], bf[ks], accA);
#pragma unroll
    for (int ks = 0; ks < 8; ++ks) accB = MFMA32(whB[ks], bf[ks], accB);
    f16* zrow = z16 + ((size_t)n * 64 + t) * 128;
#pragma unroll
    for (int q = 0; q < 4; ++q) {
      const f32x4 sa = {accA[4 * q], accA[4 * q + 1], accA[4 * q + 2], accA[4 * q + 3]};
      const f32x4 sb = {accB[4 * q], accB[4 * q + 1], accB[4 * q + 2], accB[4 * q + 3]};
      *(f16x4*)&zrow[(2 * mp) * 32 + 8 * q + 4 * hi] = pack4_relu(sa, biasA[q]);
      *(f16x4*)&zrow[(2 * mp + 1) * 32 + 8 * q + 4 * hi] = pack4_relu(sb, biasB[q]);
    }
  }
}

// ---------------------------------------------------------------------------
// conv2: out[n,t,f] = relu(b2 + sum_{k,c} W2[f,c,k] z[n, t-4+2k, c]). fp32 out.
// LDS-staged: zs[68][136] (rows 0-3 zero pad = 544 f16 = 136 f16x4 -- must
// fit under 256 threads; tid<272 f16x2 was the round-7/8 bug: threads
// 256..271 don't exist, leaving garbage in row 3 cols 104..135). 24 ks.
// ---------------------------------------------------------------------------
__global__ __launch_bounds__(256) void conv2_kernel(
    const f16* __restrict__ z16, const f16* __restrict__ w2h,
    const float* __restrict__ b2, float* __restrict__ out) {
  __shared__ f16 zs[68 * 136];
  const int tid = threadIdx.x;
  const int w = tid >> 6, lane = tid & 63;
  const int s = w >> 1, th = w & 1;
  const int rl = lane & 31, hi = lane >> 5;
  f16x8 wh[24];
#pragma unroll
  for (int ks = 0; ks < 24; ++ks)
    wh[ks] = *(const f16x8*)&w2h[((s * 24 + ks) * 64 + lane) * 8];
  f32x4 bias[4];
#pragma unroll
  for (int q = 0; q < 4; ++q) bias[q] = *(const f32x4*)&b2[s * 32 + 8 * q + 4 * hi];
  if (tid < 136) ((f16x4*)zs)[tid] = (f16x4){(f16)0, (f16)0, (f16)0, (f16)0};

  for (int g = 0; g < NG; ++g) {
    const int n = blockIdx.x * NG + g;
    const f16* zn = z16 + (size_t)n * (TDIM * HIDDIM);
    if (g) __syncthreads();
#pragma unroll
    for (int pass = 0; pass < 4; ++pass) {  // 64 rows x 16 chunks of 8 f16
      const int idx = pass * 256 + tid;
      const int row = idx >> 4, c8 = (idx & 15) * 8;
      *(f16x8*)&zs[(row + 4) * 136 + c8] = *(const f16x8*)&zn[row * 128 + c8];
    }
    __syncthreads();

    f32x16 acc;
#pragma unroll
    for (int i = 0; i < 16; ++i) acc[i] = 0.f;
#pragma unroll
    for (int ks = 0; ks < 24; ++ks) {
      const int k = ks >> 3;
      const int c0 = (ks & 7) * 16 + hi * 8;
      const f16x8 b = *(const f16x8*)&zs[(th * 32 + rl + 2 * k) * 136 + c0];
      acc = MFMA32(wh[ks], b, acc);
    }
    const int t = th * 32 + rl;
    float* orow = out + ((size_t)n * 64 + t) * 64;
#pragma unroll
    for (int q = 0; q < 4; ++q) {
      f32x4 v;
      v[0] = fmaxf(acc[4 * q + 0] + bias[q][0], 0.f);
      v[1] = fmaxf(acc[4 * q + 1] + bias[q][1], 0.f);
      v[2] = fmaxf(acc[4 * q + 2] + bias[q][2], 0.f);
      v[3] = fmaxf(acc[4 * q + 3] + bias[q][3], 0.f);
      *(f32x4*)&orow[s * 32 + 8 * q + 4 * hi] = v;
    }
  }
}

// ---------------------------------------------------------------------------
// Workspace (f16 units): w1h 12288 | wfh 16384 | w2h 24576 |
//   h16 41M (n-major) | h16t 41M (t-major) | agg16 41M | z16 82M  ~410 MB.
// ---------------------------------------------------------------------------
extern "C" void kernel_launch(void* const* d_in, const int* in_sizes, int n_in,
                              void* d_out, int out_size, void* d_ws, size_t ws_size,
                              hipStream_t stream) {
  (void)in_sizes; (void)n_in; (void)out_size; (void)ws_size;
  const float* x   = (const float*)d_in[0];
  const float* W1  = (const float*)d_in[1];
  const float* b1  = (const float*)d_in[2];
  const float* Wfc = (const float*)d_in[3];
  const float* bfc = (const float*)d_in[4];
  const float* W2  = (const float*)d_in[5];
  const float* b2  = (const float*)d_in[6];
  const int* nidx  = (const int*)d_in[7];
  const int* nmask = (const int*)d_in[8];
  float* out = (float*)d_out;

  f16* wsf = (f16*)d_ws;
  f16* w1h = wsf;
  f16* wfh = w1h + 12288;
  f16* w2h = wfh + 16384;
  f16* h16 = w2h + 24576;
  f16* h16t = h16 + (size_t)NPTS * TDIM * FDIM;
  f16* agg16 = h16t + (size_t)NPTS * TDIM * FDIM;
  f16* z16 = agg16 + (size_t)NPTS * TDIM * FDIM;

  prep_kernel<<<96, 256, 0, stream>>>(W1, Wfc, W2, w1h, wfh, w2h);
  conv1_kernel<<<NPTS / NG, 256, 0, stream>>>(x, w1h, b1, h16, h16t);
  gather_kernel<<<GNB, 256, 0, stream>>>(h16t, nidx, nmask, agg16);
  fc_kernel<<<NPTS / NG, 256, 0, stream>>>(h16, agg16, wfh, bfc, z16);
  conv2_kernel<<<NPTS / NG, 256, 0, stream>>>(z16, w2h, b2, out);
}

// Round 11
// 343.187 us; speedup vs baseline: 6.0465x; 1.0172x over previous
//
#include <hip/hip_runtime.h>
#include <cstddef>
#include <cstdint>

#define NPTS 10000
#define TDIM 64
#define CINDIM 64
#define FDIM 64
#define HIDDIM 128
#define SDIM 8
#define NG 4     // n's per block in matmul kernels
#define GNB 4000 // gather blocks (500 per XCD)
#define GNIT 20  // gather iterations per block

typedef _Float16 f16;
typedef _Float16 f16x2 __attribute__((ext_vector_type(2)));
typedef _Float16 f16x4 __attribute__((ext_vector_type(4)));
typedef _Float16 f16x8 __attribute__((ext_vector_type(8)));
typedef float f32x4 __attribute__((ext_vector_type(4)));
typedef float f32x16 __attribute__((ext_vector_type(16)));

#define MFMA32(a, b, c) __builtin_amdgcn_mfma_f32_32x32x16_f16((a), (b), (c), 0, 0, 0)

static __device__ __forceinline__ f16x2 pk(float a, float b) {
  return __builtin_bit_cast(f16x2, __builtin_amdgcn_cvt_pkrtz(a, b));
}
static __device__ __forceinline__ f16x4 pack4(f32x4 p) {
  f16x2 h0 = pk(p[0], p[1]), h1 = pk(p[2], p[3]);
  return __builtin_shufflevector(h0, h1, 0, 1, 2, 3);
}
static __device__ __forceinline__ f16x4 pack4_relu(f32x4 v, f32x4 bias) {
  f16x4 r;
  r[0] = (f16)fmaxf(v[0] + bias[0], 0.f);
  r[1] = (f16)fmaxf(v[1] + bias[1], 0.f);
  r[2] = (f16)fmaxf(v[2] + bias[2], 0.f);
  r[3] = (f16)fmaxf(v[3] + bias[3], 0.f);
  return r;
}

// ---------------------------------------------------------------------------
// prep: round weights to f16 and pre-shuffle into 32x32x16 A-frag order:
// lane l holds A[row=l&31][kk=(l>>5)*8+j]. Storage [slice][ks][lane][j],
// kk = ks*16+(l>>5)*8+j.
//   conv1 kk = k*64 + c   (K=192, 12 ks, 2 slices)
//   fc    kk = c          (K=128,  8 ks, 4 slices)
//   conv2 kk = k*128 + c  (K=384, 24 ks, 2 slices)
// ---------------------------------------------------------------------------
__global__ __launch_bounds__(256) void prep_kernel(
    const float* __restrict__ W1, const float* __restrict__ Wfc,
    const float* __restrict__ W2, f16* __restrict__ w1h,
    f16* __restrict__ wfh, f16* __restrict__ w2h) {
  const int idx = blockIdx.x * 256 + threadIdx.x;
  const int j = idx & 7;
  if (idx < 2 * 12 * 512) {  // w1
    const int s = idx / 6144, rem = idx % 6144;
    const int ks = rem / 512, l = (rem % 512) >> 3;
    const int kk = ks * 16 + ((l >> 5) << 3) + j;
    const int k = kk >> 6, c = kk & 63, f = s * 32 + (l & 31);
    w1h[idx] = (f16)W1[f * 192 + c * 3 + k];
  }
  if (idx < 4 * 8 * 512) {  // wfc
    const int s = idx / 4096, rem = idx % 4096;
    const int ks = rem / 512, l = (rem % 512) >> 3;
    const int kk = ks * 16 + ((l >> 5) << 3) + j;
    const int hc = s * 32 + (l & 31);
    wfh[idx] = (f16)Wfc[hc * 128 + kk];
  }
  if (idx < 2 * 24 * 512) {  // w2
    const int s = idx / 12288, rem = idx % 12288;
    const int ks = rem / 512, l = (rem % 512) >> 3;
    const int kk = ks * 16 + ((l >> 5) << 3) + j;
    const int k = kk >> 7, c = kk & 127, f = s * 32 + (l & 31);
    w2h[idx] = (f16)W2[f * 384 + c * 3 + k];
  }
}

// ---------------------------------------------------------------------------
// conv1: relu(b1 + sum_{k,c} W1[f,c,k] x[n, t-4+2k, c]).
// LDS-staged: x[n] tile (64x64 fp32) loaded coalesced (16 thr/row, 16B/thr),
// packed to f16 into xs[68][72] (rows 0-3 = causal zero pad; +8 f16 row pad).
// Wave w: M-slice s=w>>1 (f in [32s,32s+32)), t-half th=w&1.
// Writes h in n-major (h16, for fc) and t-major (h16t, for gather).
// ---------------------------------------------------------------------------
__global__ __launch_bounds__(256) void conv1_kernel(
    const float* __restrict__ x, const f16* __restrict__ w1h,
    const float* __restrict__ b1, f16* __restrict__ h16,
    f16* __restrict__ h16t) {
  __shared__ f16 xs[68 * 72];
  const int tid = threadIdx.x;
  const int w = tid >> 6, lane = tid & 63;
  const int s = w >> 1, th = w & 1;
  const int rl = lane & 31, hi = lane >> 5;
  f16x8 wh[12];
#pragma unroll
  for (int ks = 0; ks < 12; ++ks)
    wh[ks] = *(const f16x8*)&w1h[((s * 12 + ks) * 64 + lane) * 8];
  f32x4 bias[4];
#pragma unroll
  for (int q = 0; q < 4; ++q) bias[q] = *(const f32x4*)&b1[s * 32 + 8 * q + 4 * hi];
  // rows 0-3 (causal pad) = 288 f16 = 144 f16x2; 144 <= 256 threads -> full.
  if (tid < 144) ((f16x2*)xs)[tid] = (f16x2){(f16)0, (f16)0};

  for (int g = 0; g < NG; ++g) {
    const int n = blockIdx.x * NG + g;
    const float* xn = x + (size_t)n * (TDIM * CINDIM);
    if (g) __syncthreads();  // previous compute done before overwrite
#pragma unroll
    for (int pass = 0; pass < 4; ++pass) {  // 64 rows x 16 chunks of 4 fp32
      const int idx = pass * 256 + tid;
      const int row = idx >> 4, c4 = (idx & 15) * 4;
      const f32x4 v = *(const f32x4*)&xn[row * 64 + c4];
      *(f16x4*)&xs[(row + 4) * 72 + c4] = pack4(v);
    }
    __syncthreads();

    f32x16 acc;
#pragma unroll
    for (int i = 0; i < 16; ++i) acc[i] = 0.f;
#pragma unroll
    for (int ks = 0; ks < 12; ++ks) {
      const int k = ks >> 2;
      const int c0 = (ks & 3) * 16 + hi * 8;
      const f16x8 b = *(const f16x8*)&xs[(th * 32 + rl + 2 * k) * 72 + c0];
      acc = MFMA32(wh[ks], b, acc);
    }
    const int t = th * 32 + rl;
    f16* hrow = h16 + ((size_t)n * 64 + t) * 64;
    f16* hrowt = h16t + ((size_t)t * NPTS + n) * 64;
#pragma unroll
    for (int q = 0; q < 4; ++q) {
      const f32x4 sub = {acc[4 * q], acc[4 * q + 1], acc[4 * q + 2], acc[4 * q + 3]};
      const f16x4 v = pack4_relu(sub, bias[q]);
      *(f16x4*)&hrow[s * 32 + 8 * q + 4 * hi] = v;
      *(f16x4*)&hrowt[s * 32 + 8 * q + 4 * hi] = v;
    }
  }
}

// ---------------------------------------------------------------------------
// gather: agg[n][t][:] = masked-mean_s h16t[t][idx[t,n,s]][:] (fallback self).
// Round-9 structure (known good) with: GNB 2000->4000 (occupancy 70->~95%),
// incremental (t,n) tracking instead of per-iteration p/10000 division.
// Per XCD: offset o = q*8+hw covers [0,4000), stride 4000 x 20 iters covers
// o in [0,80000) exactly once; t = xcd*8 + o/10000, n = o%10000.
// idx/mask prefetched one iter ahead; gather loads unconditional.
// ---------------------------------------------------------------------------
__global__ __launch_bounds__(256) void gather_kernel(
    const f16* __restrict__ h16t, const int* __restrict__ nidx,
    const int* __restrict__ nmask, f16* __restrict__ agg16) {
  const int tid = threadIdx.x;
  const int hw = tid >> 5, lane32 = tid & 31;
  const int xcd = blockIdx.x & 7, q = blockIdx.x >> 3;  // q in [0,500)
  const uint32_t* h32 = (const uint32_t*)h16t;
  uint32_t* agg32 = (uint32_t*)agg16;

  int t = xcd * 8;
  int n = q * 8 + hw;  // o in [0,4000)
  int4 ci0, ci1, cm0, cm1;
  {
    const size_t pr = ((size_t)t * NPTS + n) * SDIM;
    ci0 = *(const int4*)&nidx[pr];
    ci1 = *(const int4*)&nidx[pr + 4];
    cm0 = *(const int4*)&nmask[pr];
    cm1 = *(const int4*)&nmask[pr + 4];
  }
  for (int j = 0; j < GNIT; ++j) {
    // next (t,n): o += GNB; GNB < NPTS so at most one wrap
    int tn = t, nn = n + GNB;
    if (nn >= NPTS) { nn -= NPTS; ++tn; }
    int4 pi0 = {0, 0, 0, 0}, pi1 = {0, 0, 0, 0};
    int4 pm0 = {0, 0, 0, 0}, pm1 = {0, 0, 0, 0};
    if (j + 1 < GNIT) {  // prefetch next pair's idx/mask
      const size_t pr = ((size_t)tn * NPTS + nn) * SDIM;
      pi0 = *(const int4*)&nidx[pr];
      pi1 = *(const int4*)&nidx[pr + 4];
      pm0 = *(const int4*)&nmask[pr];
      pm1 = *(const int4*)&nmask[pr + 4];
    }
    const uint32_t tb = (uint32_t)t * (NPTS * 32) + lane32;
    const int idx8[8] = {ci0.x, ci0.y, ci0.z, ci0.w, ci1.x, ci1.y, ci1.z, ci1.w};
    const int msk8[8] = {cm0.x, cm0.y, cm0.z, cm0.w, cm1.x, cm1.y, cm1.z, cm1.w};
    uint32_t u[8];
#pragma unroll
    for (int sidx = 0; sidx < SDIM; ++sidx)
      u[sidx] = h32[tb + (uint32_t)idx8[sidx] * 32u];
    float ax = 0.f, ay = 0.f, cnt = 0.f;
#pragma unroll
    for (int sidx = 0; sidx < SDIM; ++sidx) {
      const float m = (msk8[sidx] != 0) ? 1.f : 0.f;
      const f16x2 hv = __builtin_bit_cast(f16x2, u[sidx]);
      ax = fmaf(m, (float)hv[0], ax);
      ay = fmaf(m, (float)hv[1], ay);
      cnt += m;
    }
    f16x2 outv;
    if (cnt > 0.f) {
      const float inv = 1.f / cnt;
      outv[0] = (f16)(ax * inv);
      outv[1] = (f16)(ay * inv);
    } else {
      const uint32_t su = h32[tb + (uint32_t)n * 32u];
      outv = __builtin_bit_cast(f16x2, su);
    }
    agg32[((size_t)n * 64 + t) * 32 + lane32] = __builtin_bit_cast(uint32_t, outv);
    ci0 = pi0; ci1 = pi1; cm0 = pm0; cm1 = pm1;
    t = tn; n = nn;
  }
}

// ---------------------------------------------------------------------------
// fc: z[n][t][hc] = relu(bfc + sum_c [h|agg][n,t,c] Wfc[hc,c]).
// LDS-staged: hs/as tiles (64x64 f16 each, +8 pad). Wave w: M-pair mp=w>>1
// (hc slices {2mp,2mp+1}), t-half th=w&1.
// ---------------------------------------------------------------------------
__global__ __launch_bounds__(256) void fc_kernel(
    const f16* __restrict__ h16, const f16* __restrict__ agg16,
    const f16* __restrict__ wfh, const float* __restrict__ bfc,
    f16* __restrict__ z16) {
  __shared__ f16 hs[64 * 72];
  __shared__ f16 as2[64 * 72];
  const int tid = threadIdx.x;
  const int w = tid >> 6, lane = tid & 63;
  const int mp = w >> 1, th = w & 1;
  const int rl = lane & 31, hi = lane >> 5;
  f16x8 whA[8], whB[8];
#pragma unroll
  for (int ks = 0; ks < 8; ++ks) {
    whA[ks] = *(const f16x8*)&wfh[(((2 * mp) * 8 + ks) * 64 + lane) * 8];
    whB[ks] = *(const f16x8*)&wfh[(((2 * mp + 1) * 8 + ks) * 64 + lane) * 8];
  }
  f32x4 biasA[4], biasB[4];
#pragma unroll
  for (int q = 0; q < 4; ++q) {
    biasA[q] = *(const f32x4*)&bfc[(2 * mp) * 32 + 8 * q + 4 * hi];
    biasB[q] = *(const f32x4*)&bfc[(2 * mp + 1) * 32 + 8 * q + 4 * hi];
  }
  const int t = th * 32 + rl;
  for (int g = 0; g < NG; ++g) {
    const int n = blockIdx.x * NG + g;
    if (g) __syncthreads();
#pragma unroll
    for (int pass = 0; pass < 2; ++pass) {  // 64 rows x 8 chunks of 8 f16
      const int idx = pass * 256 + tid;
      const int row = idx >> 3, c8 = (idx & 7) * 8;
      *(f16x8*)&hs[row * 72 + c8] =
          *(const f16x8*)&h16[((size_t)n * 64 + row) * 64 + c8];
      *(f16x8*)&as2[row * 72 + c8] =
          *(const f16x8*)&agg16[((size_t)n * 64 + row) * 64 + c8];
    }
    __syncthreads();

    f32x16 accA, accB;
#pragma unroll
    for (int i = 0; i < 16; ++i) { accA[i] = 0.f; accB[i] = 0.f; }
    f16x8 bf[8];
#pragma unroll
    for (int ks = 0; ks < 8; ++ks) {
      const int c0 = (ks & 3) * 16 + hi * 8;
      bf[ks] = (ks < 4) ? *(const f16x8*)&hs[t * 72 + c0]
                        : *(const f16x8*)&as2[t * 72 + c0];
    }
#pragma unroll
    for (int ks = 0; ks < 8; ++ks) accA = MFMA32(whA[ks], bf[ks], accA);
#pragma unroll
    for (int ks = 0; ks < 8; ++ks) accB = MFMA32(whB[ks], bf[ks], accB);
    f16* zrow = z16 + ((size_t)n * 64 + t) * 128;
#pragma unroll
    for (int q = 0; q < 4; ++q) {
      const f32x4 sa = {accA[4 * q], accA[4 * q + 1], accA[4 * q + 2], accA[4 * q + 3]};
      const f32x4 sb = {accB[4 * q], accB[4 * q + 1], accB[4 * q + 2], accB[4 * q + 3]};
      *(f16x4*)&zrow[(2 * mp) * 32 + 8 * q + 4 * hi] = pack4_relu(sa, biasA[q]);
      *(f16x4*)&zrow[(2 * mp + 1) * 32 + 8 * q + 4 * hi] = pack4_relu(sb, biasB[q]);
    }
  }
}

// ---------------------------------------------------------------------------
// conv2: out[n,t,f] = relu(b2 + sum_{k,c} W2[f,c,k] z[n, t-4+2k, c]). fp32 out.
// LDS-staged: zs[68][136] (rows 0-3 zero pad = 544 f16 = 136 f16x4, within
// 256 threads). 24 ks.
// ---------------------------------------------------------------------------
__global__ __launch_bounds__(256) void conv2_kernel(
    const f16* __restrict__ z16, const f16* __restrict__ w2h,
    const float* __restrict__ b2, float* __restrict__ out) {
  __shared__ f16 zs[68 * 136];
  const int tid = threadIdx.x;
  const int w = tid >> 6, lane = tid & 63;
  const int s = w >> 1, th = w & 1;
  const int rl = lane & 31, hi = lane >> 5;
  f16x8 wh[24];
#pragma unroll
  for (int ks = 0; ks < 24; ++ks)
    wh[ks] = *(const f16x8*)&w2h[((s * 24 + ks) * 64 + lane) * 8];
  f32x4 bias[4];
#pragma unroll
  for (int q = 0; q < 4; ++q) bias[q] = *(const f32x4*)&b2[s * 32 + 8 * q + 4 * hi];
  if (tid < 136) ((f16x4*)zs)[tid] = (f16x4){(f16)0, (f16)0, (f16)0, (f16)0};

  for (int g = 0; g < NG; ++g) {
    const int n = blockIdx.x * NG + g;
    const f16* zn = z16 + (size_t)n * (TDIM * HIDDIM);
    if (g) __syncthreads();
#pragma unroll
    for (int pass = 0; pass < 4; ++pass) {  // 64 rows x 16 chunks of 8 f16
      const int idx = pass * 256 + tid;
      const int row = idx >> 4, c8 = (idx & 15) * 8;
      *(f16x8*)&zs[(row + 4) * 136 + c8] = *(const f16x8*)&zn[row * 128 + c8];
    }
    __syncthreads();

    f32x16 acc;
#pragma unroll
    for (int i = 0; i < 16; ++i) acc[i] = 0.f;
#pragma unroll
    for (int ks = 0; ks < 24; ++ks) {
      const int k = ks >> 3;
      const int c0 = (ks & 7) * 16 + hi * 8;
      const f16x8 b = *(const f16x8*)&zs[(th * 32 + rl + 2 * k) * 136 + c0];
      acc = MFMA32(wh[ks], b, acc);
    }
    const int t = th * 32 + rl;
    float* orow = out + ((size_t)n * 64 + t) * 64;
#pragma unroll
    for (int q = 0; q < 4; ++q) {
      f32x4 v;
      v[0] = fmaxf(acc[4 * q + 0] + bias[q][0], 0.f);
      v[1] = fmaxf(acc[4 * q + 1] + bias[q][1], 0.f);
      v[2] = fmaxf(acc[4 * q + 2] + bias[q][2], 0.f);
      v[3] = fmaxf(acc[4 * q + 3] + bias[q][3], 0.f);
      *(f32x4*)&orow[s * 32 + 8 * q + 4 * hi] = v;
    }
  }
}

// ---------------------------------------------------------------------------
// Workspace (f16 units): w1h 12288 | wfh 16384 | w2h 24576 |
//   h16 41M (n-major) | h16t 41M (t-major) | agg16 41M | z16 82M  ~410 MB.
// ---------------------------------------------------------------------------
extern "C" void kernel_launch(void* const* d_in, const int* in_sizes, int n_in,
                              void* d_out, int out_size, void* d_ws, size_t ws_size,
                              hipStream_t stream) {
  (void)in_sizes; (void)n_in; (void)out_size; (void)ws_size;
  const float* x   = (const float*)d_in[0];
  const float* W1  = (const float*)d_in[1];
  const float* b1  = (const float*)d_in[2];
  const float* Wfc = (const float*)d_in[3];
  const float* bfc = (const float*)d_in[4];
  const float* W2  = (const float*)d_in[5];
  const float* b2  = (const float*)d_in[6];
  const int* nidx  = (const int*)d_in[7];
  const int* nmask = (const int*)d_in[8];
  float* out = (float*)d_out;

  f16* wsf = (f16*)d_ws;
  f16* w1h = wsf;
  f16* wfh = w1h + 12288;
  f16* w2h = wfh + 16384;
  f16* h16 = w2h + 24576;
  f16* h16t = h16 + (size_t)NPTS * TDIM * FDIM;
  f16* agg16 = h16t + (size_t)NPTS * TDIM * FDIM;
  f16* z16 = agg16 + (size_t)NPTS * TDIM * FDIM;

  prep_kernel<<<96, 256, 0, stream>>>(W1, Wfc, W2, w1h, wfh, w2h);
  conv1_kernel<<<NPTS / NG, 256, 0, stream>>>(x, w1h, b1, h16, h16t);
  gather_kernel<<<GNB, 256, 0, stream>>>(h16t, nidx, nmask, agg16);
  fc_kernel<<<NPTS / NG, 256, 0, stream>>>(h16, agg16, wfh, bfc, z16);
  conv2_kernel<<<NPTS / NG, 256, 0, stream>>>(z16, w2h, b2, out);
}

// Round 12
// 324.838 us; speedup vs baseline: 6.3881x; 1.0565x over previous
//
#include <hip/hip_runtime.h>
#include <cstddef>
#include <cstdint>

#define NPTS 10000
#define TDIM 64
#define CINDIM 64
#define FDIM 64
#define HIDDIM 128
#define SDIM 8
#define NG 4     // n's per block in matmul kernels
#define GNB 4000 // gather blocks (500 per XCD)

typedef _Float16 f16;
typedef _Float16 f16x2 __attribute__((ext_vector_type(2)));
typedef _Float16 f16x4 __attribute__((ext_vector_type(4)));
typedef _Float16 f16x8 __attribute__((ext_vector_type(8)));
typedef float f32x4 __attribute__((ext_vector_type(4)));
typedef float f32x16 __attribute__((ext_vector_type(16)));

#define MFMA32(a, b, c) __builtin_amdgcn_mfma_f32_32x32x16_f16((a), (b), (c), 0, 0, 0)

static __device__ __forceinline__ f16x2 pk(float a, float b) {
  return __builtin_bit_cast(f16x2, __builtin_amdgcn_cvt_pkrtz(a, b));
}
static __device__ __forceinline__ f16x4 pack4(f32x4 p) {
  f16x2 h0 = pk(p[0], p[1]), h1 = pk(p[2], p[3]);
  return __builtin_shufflevector(h0, h1, 0, 1, 2, 3);
}
static __device__ __forceinline__ f16x4 pack4_relu(f32x4 v, f32x4 bias) {
  f16x4 r;
  r[0] = (f16)fmaxf(v[0] + bias[0], 0.f);
  r[1] = (f16)fmaxf(v[1] + bias[1], 0.f);
  r[2] = (f16)fmaxf(v[2] + bias[2], 0.f);
  r[3] = (f16)fmaxf(v[3] + bias[3], 0.f);
  return r;
}

// ---------------------------------------------------------------------------
// prep: round weights to f16 and pre-shuffle into 32x32x16 A-frag order:
// lane l holds A[row=l&31][kk=(l>>5)*8+j]. Storage [slice][ks][lane][j],
// kk = ks*16+(l>>5)*8+j.
//   conv1 kk = k*64 + c   (K=192, 12 ks, 2 slices)
//   fc    kk = c          (K=128,  8 ks, 4 slices)
//   conv2 kk = k*128 + c  (K=384, 24 ks, 2 slices)
// ---------------------------------------------------------------------------
__global__ __launch_bounds__(256) void prep_kernel(
    const float* __restrict__ W1, const float* __restrict__ Wfc,
    const float* __restrict__ W2, f16* __restrict__ w1h,
    f16* __restrict__ wfh, f16* __restrict__ w2h) {
  const int idx = blockIdx.x * 256 + threadIdx.x;
  const int j = idx & 7;
  if (idx < 2 * 12 * 512) {  // w1
    const int s = idx / 6144, rem = idx % 6144;
    const int ks = rem / 512, l = (rem % 512) >> 3;
    const int kk = ks * 16 + ((l >> 5) << 3) + j;
    const int k = kk >> 6, c = kk & 63, f = s * 32 + (l & 31);
    w1h[idx] = (f16)W1[f * 192 + c * 3 + k];
  }
  if (idx < 4 * 8 * 512) {  // wfc
    const int s = idx / 4096, rem = idx % 4096;
    const int ks = rem / 512, l = (rem % 512) >> 3;
    const int kk = ks * 16 + ((l >> 5) << 3) + j;
    const int hc = s * 32 + (l & 31);
    wfh[idx] = (f16)Wfc[hc * 128 + kk];
  }
  if (idx < 2 * 24 * 512) {  // w2
    const int s = idx / 12288, rem = idx % 12288;
    const int ks = rem / 512, l = (rem % 512) >> 3;
    const int kk = ks * 16 + ((l >> 5) << 3) + j;
    const int k = kk >> 7, c = kk & 127, f = s * 32 + (l & 31);
    w2h[idx] = (f16)W2[f * 384 + c * 3 + k];
  }
}

// ---------------------------------------------------------------------------
// conv1: relu(b1 + sum_{k,c} W1[f,c,k] x[n, t-4+2k, c]).
// LDS-staged: x[n] tile (64x64 fp32) loaded coalesced (16 thr/row, 16B/thr),
// packed to f16 into xs[68][72] (rows 0-3 = causal zero pad; +8 f16 row pad).
// Wave w: M-slice s=w>>1 (f in [32s,32s+32)), t-half th=w&1.
// Writes h in n-major (h16, for fc) and t-major (h16t, for gather).
// ---------------------------------------------------------------------------
__global__ __launch_bounds__(256) void conv1_kernel(
    const float* __restrict__ x, const f16* __restrict__ w1h,
    const float* __restrict__ b1, f16* __restrict__ h16,
    f16* __restrict__ h16t) {
  __shared__ f16 xs[68 * 72];
  const int tid = threadIdx.x;
  const int w = tid >> 6, lane = tid & 63;
  const int s = w >> 1, th = w & 1;
  const int rl = lane & 31, hi = lane >> 5;
  f16x8 wh[12];
#pragma unroll
  for (int ks = 0; ks < 12; ++ks)
    wh[ks] = *(const f16x8*)&w1h[((s * 12 + ks) * 64 + lane) * 8];
  f32x4 bias[4];
#pragma unroll
  for (int q = 0; q < 4; ++q) bias[q] = *(const f32x4*)&b1[s * 32 + 8 * q + 4 * hi];
  // rows 0-3 (causal pad) = 288 f16 = 144 f16x2; 144 <= 256 threads -> full.
  if (tid < 144) ((f16x2*)xs)[tid] = (f16x2){(f16)0, (f16)0};

  for (int g = 0; g < NG; ++g) {
    const int n = blockIdx.x * NG + g;
    const float* xn = x + (size_t)n * (TDIM * CINDIM);
    if (g) __syncthreads();  // previous compute done before overwrite
#pragma unroll
    for (int pass = 0; pass < 4; ++pass) {  // 64 rows x 16 chunks of 4 fp32
      const int idx = pass * 256 + tid;
      const int row = idx >> 4, c4 = (idx & 15) * 4;
      const f32x4 v = *(const f32x4*)&xn[row * 64 + c4];
      *(f16x4*)&xs[(row + 4) * 72 + c4] = pack4(v);
    }
    __syncthreads();

    f32x16 acc;
#pragma unroll
    for (int i = 0; i < 16; ++i) acc[i] = 0.f;
#pragma unroll
    for (int ks = 0; ks < 12; ++ks) {
      const int k = ks >> 2;
      const int c0 = (ks & 3) * 16 + hi * 8;
      const f16x8 b = *(const f16x8*)&xs[(th * 32 + rl + 2 * k) * 72 + c0];
      acc = MFMA32(wh[ks], b, acc);
    }
    const int t = th * 32 + rl;
    f16* hrow = h16 + ((size_t)n * 64 + t) * 64;
    f16* hrowt = h16t + ((size_t)t * NPTS + n) * 64;
#pragma unroll
    for (int q = 0; q < 4; ++q) {
      const f32x4 sub = {acc[4 * q], acc[4 * q + 1], acc[4 * q + 2], acc[4 * q + 3]};
      const f16x4 v = pack4_relu(sub, bias[q]);
      *(f16x4*)&hrow[s * 32 + 8 * q + 4 * hi] = v;
      *(f16x4*)&hrowt[s * 32 + 8 * q + 4 * hi] = v;
    }
  }
}

// ---------------------------------------------------------------------------
// gather: agg[n][t][:] = masked-mean_s h16t[t][idx[t,n,s]][:] (fallback self).
// Quarter-wave per (t,n) pair: lane = q4*16+sl reads 8B of pair q4's rows ->
// one wave64 gather instruction serves 4 pairs (4x128B rows). idx/mask for
// all 4 pairs loaded by one instruction (lane reads elem (l>>4)*8+(l&7)) and
// broadcast to the owning quarter via __shfl(v,(lane&48)+s). VMEM per 4
// pairs: 52 -> 11. Walk (stride 8000/iter, 10 iters) and XCD slab affinity
// identical to round 11; a quad {o..o+3} never straddles t (10000%4==0).
// ---------------------------------------------------------------------------
__global__ __launch_bounds__(256) void gather_kernel(
    const f16* __restrict__ h16t, const int* __restrict__ nidx,
    const int* __restrict__ nmask, f16* __restrict__ agg16) {
  const int tid = threadIdx.x;
  const int wv = tid >> 6, lane = tid & 63;
  const int q4 = lane >> 4, sl = lane & 15;             // quarter, sublane
  const int xcd = blockIdx.x & 7, q = blockIdx.x >> 3;  // q in [0,500)
  const uint2* h64 = (const uint2*)h16t;                // 8B units
  uint2* agg64 = (uint2*)agg16;

  int t = xcd * 8;
  int n = (q * 4 + wv) * 4;          // quad base in [0,8000), 4-aligned
  const int eo = q4 * 8 + (lane & 7);  // this lane's idx/mask element
  int ci, cm;
  {
    const size_t pr = ((size_t)t * NPTS + n) * SDIM;
    ci = nidx[pr + eo];
    cm = nmask[pr + eo];
  }
  for (int j = 0; j < 10; ++j) {
    int tn = t, nn = n + 8000;
    if (nn >= NPTS) { nn -= NPTS; ++tn; }  // stride < NPTS: at most one wrap
    int pi = 0, pm = 0;
    if (j + 1 < 10) {  // prefetch next quad's idx/mask
      const size_t pr = ((size_t)tn * NPTS + nn) * SDIM;
      pi = nidx[pr + eo];
      pm = nmask[pr + eo];
    }
    const uint32_t tb = (uint32_t)t * (NPTS * 16) + sl;  // uint2 units
    uint2 u[8];
#pragma unroll
    for (int s = 0; s < SDIM; ++s) {
      const int is = __shfl(ci, (lane & 48) + s, 64);
      u[s] = h64[tb + (uint32_t)is * 16u];
    }
    float a0 = 0.f, a1 = 0.f, a2 = 0.f, a3 = 0.f, cnt = 0.f;
#pragma unroll
    for (int s = 0; s < SDIM; ++s) {
      const float m = (__shfl(cm, (lane & 48) + s, 64) != 0) ? 1.f : 0.f;
      const f16x2 lo = __builtin_bit_cast(f16x2, u[s].x);
      const f16x2 hi = __builtin_bit_cast(f16x2, u[s].y);
      a0 = fmaf(m, (float)lo[0], a0);
      a1 = fmaf(m, (float)lo[1], a1);
      a2 = fmaf(m, (float)hi[0], a2);
      a3 = fmaf(m, (float)hi[1], a3);
      cnt += m;
    }
    uint2 outv;
    if (cnt > 0.f) {
      const float inv = 1.f / cnt;
      const f16x4 o4 = pack4((f32x4){a0 * inv, a1 * inv, a2 * inv, a3 * inv});
      outv = __builtin_bit_cast(uint2, o4);
    } else {  // fallback: self row (exec-masked; skipped when no lane needs it)
      outv = h64[tb + (uint32_t)(n + q4) * 16u];
    }
    agg64[((size_t)(n + q4) * 64 + t) * 16 + sl] = outv;
    ci = pi; cm = pm; t = tn; n = nn;
  }
}

// ---------------------------------------------------------------------------
// fc: z[n][t][hc] = relu(bfc + sum_c [h|agg][n,t,c] Wfc[hc,c]).
// LDS-staged: hs/as tiles (64x64 f16 each, +8 pad). Wave w: M-pair mp=w>>1
// (hc slices {2mp,2mp+1}), t-half th=w&1.
// ---------------------------------------------------------------------------
__global__ __launch_bounds__(256) void fc_kernel(
    const f16* __restrict__ h16, const f16* __restrict__ agg16,
    const f16* __restrict__ wfh, const float* __restrict__ bfc,
    f16* __restrict__ z16) {
  __shared__ f16 hs[64 * 72];
  __shared__ f16 as2[64 * 72];
  const int tid = threadIdx.x;
  const int w = tid >> 6, lane = tid & 63;
  const int mp = w >> 1, th = w & 1;
  const int rl = lane & 31, hi = lane >> 5;
  f16x8 whA[8], whB[8];
#pragma unroll
  for (int ks = 0; ks < 8; ++ks) {
    whA[ks] = *(const f16x8*)&wfh[(((2 * mp) * 8 + ks) * 64 + lane) * 8];
    whB[ks] = *(const f16x8*)&wfh[(((2 * mp + 1) * 8 + ks) * 64 + lane) * 8];
  }
  f32x4 biasA[4], biasB[4];
#pragma unroll
  for (int q = 0; q < 4; ++q) {
    biasA[q] = *(const f32x4*)&bfc[(2 * mp) * 32 + 8 * q + 4 * hi];
    biasB[q] = *(const f32x4*)&bfc[(2 * mp + 1) * 32 + 8 * q + 4 * hi];
  }
  const int t = th * 32 + rl;
  for (int g = 0; g < NG; ++g) {
    const int n = blockIdx.x * NG + g;
    if (g) __syncthreads();
#pragma unroll
    for (int pass = 0; pass < 2; ++pass) {  // 64 rows x 8 chunks of 8 f16
      const int idx = pass * 256 + tid;
      const int row = idx >> 3, c8 = (idx & 7) * 8;
      *(f16x8*)&hs[row * 72 + c8] =
          *(const f16x8*)&h16[((size_t)n * 64 + row) * 64 + c8];
      *(f16x8*)&as2[row * 72 + c8] =
          *(const f16x8*)&agg16[((size_t)n * 64 + row) * 64 + c8];
    }
    __syncthreads();

    f32x16 accA, accB;
#pragma unroll
    for (int i = 0; i < 16; ++i) { accA[i] = 0.f; accB[i] = 0.f; }
    f16x8 bf[8];
#pragma unroll
    for (int ks = 0; ks < 8; ++ks) {
      const int c0 = (ks & 3) * 16 + hi * 8;
      bf[ks] = (ks < 4) ? *(const f16x8*)&hs[t * 72 + c0]
                        : *(const f16x8*)&as2[t * 72 + c0];
    }
#pragma unroll
    for (int ks = 0; ks < 8; ++ks) accA = MFMA32(whA[ks], bf[ks], accA);
#pragma unroll
    for (int ks = 0; ks < 8; ++ks) accB = MFMA32(whB[ks], bf[ks], accB);
    f16* zrow = z16 + ((size_t)n * 64 + t) * 128;
#pragma unroll
    for (int q = 0; q < 4; ++q) {
      const f32x4 sa = {accA[4 * q], accA[4 * q + 1], accA[4 * q + 2], accA[4 * q + 3]};
      const f32x4 sb = {accB[4 * q], accB[4 * q + 1], accB[4 * q + 2], accB[4 * q + 3]};
      *(f16x4*)&zrow[(2 * mp) * 32 + 8 * q + 4 * hi] = pack4_relu(sa, biasA[q]);
      *(f16x4*)&zrow[(2 * mp + 1) * 32 + 8 * q + 4 * hi] = pack4_relu(sb, biasB[q]);
    }
  }
}

// ---------------------------------------------------------------------------
// conv2: out[n,t,f] = relu(b2 + sum_{k,c} W2[f,c,k] z[n, t-4+2k, c]). fp32 out.
// LDS-staged: zs[68][136] (rows 0-3 zero pad = 544 f16 = 136 f16x4, within
// 256 threads). 24 ks.
// ---------------------------------------------------------------------------
__global__ __launch_bounds__(256) void conv2_kernel(
    const f16* __restrict__ z16, const f16* __restrict__ w2h,
    const float* __restrict__ b2, float* __restrict__ out) {
  __shared__ f16 zs[68 * 136];
  const int tid = threadIdx.x;
  const int w = tid >> 6, lane = tid & 63;
  const int s = w >> 1, th = w & 1;
  const int rl = lane & 31, hi = lane >> 5;
  f16x8 wh[24];
#pragma unroll
  for (int ks = 0; ks < 24; ++ks)
    wh[ks] = *(const f16x8*)&w2h[((s * 24 + ks) * 64 + lane) * 8];
  f32x4 bias[4];
#pragma unroll
  for (int q = 0; q < 4; ++q) bias[q] = *(const f32x4*)&b2[s * 32 + 8 * q + 4 * hi];
  if (tid < 136) ((f16x4*)zs)[tid] = (f16x4){(f16)0, (f16)0, (f16)0, (f16)0};

  for (int g = 0; g < NG; ++g) {
    const int n = blockIdx.x * NG + g;
    const f16* zn = z16 + (size_t)n * (TDIM * HIDDIM);
    if (g) __syncthreads();
#pragma unroll
    for (int pass = 0; pass < 4; ++pass) {  // 64 rows x 16 chunks of 8 f16
      const int idx = pass * 256 + tid;
      const int row = idx >> 4, c8 = (idx & 15) * 8;
      *(f16x8*)&zs[(row + 4) * 136 + c8] = *(const f16x8*)&zn[row * 128 + c8];
    }
    __syncthreads();

    f32x16 acc;
#pragma unroll
    for (int i = 0; i < 16; ++i) acc[i] = 0.f;
#pragma unroll
    for (int ks = 0; ks < 24; ++ks) {
      const int k = ks >> 3;
      const int c0 = (ks & 7) * 16 + hi * 8;
      const f16x8 b = *(const f16x8*)&zs[(th * 32 + rl + 2 * k) * 136 + c0];
      acc = MFMA32(wh[ks], b, acc);
    }
    const int t = th * 32 + rl;
    float* orow = out + ((size_t)n * 64 + t) * 64;
#pragma unroll
    for (int q = 0; q < 4; ++q) {
      f32x4 v;
      v[0] = fmaxf(acc[4 * q + 0] + bias[q][0], 0.f);
      v[1] = fmaxf(acc[4 * q + 1] + bias[q][1], 0.f);
      v[2] = fmaxf(acc[4 * q + 2] + bias[q][2], 0.f);
      v[3] = fmaxf(acc[4 * q + 3] + bias[q][3], 0.f);
      *(f32x4*)&orow[s * 32 + 8 * q + 4 * hi] = v;
    }
  }
}

// ---------------------------------------------------------------------------
// Workspace (f16 units): w1h 12288 | wfh 16384 | w2h 24576 |
//   h16 41M (n-major) | h16t 41M (t-major) | agg16 41M | z16 82M  ~410 MB.
// ---------------------------------------------------------------------------
extern "C" void kernel_launch(void* const* d_in, const int* in_sizes, int n_in,
                              void* d_out, int out_size, void* d_ws, size_t ws_size,
                              hipStream_t stream) {
  (void)in_sizes; (void)n_in; (void)out_size; (void)ws_size;
  const float* x   = (const float*)d_in[0];
  const float* W1  = (const float*)d_in[1];
  const float* b1  = (const float*)d_in[2];
  const float* Wfc = (const float*)d_in[3];
  const float* bfc = (const float*)d_in[4];
  const float* W2  = (const float*)d_in[5];
  const float* b2  = (const float*)d_in[6];
  const int* nidx  = (const int*)d_in[7];
  const int* nmask = (const int*)d_in[8];
  float* out = (float*)d_out;

  f16* wsf = (f16*)d_ws;
  f16* w1h = wsf;
  f16* wfh = w1h + 12288;
  f16* w2h = wfh + 16384;
  f16* h16 = w2h + 24576;
  f16* h16t = h16 + (size_t)NPTS * TDIM * FDIM;
  f16* agg16 = h16t + (size_t)NPTS * TDIM * FDIM;
  f16* z16 = agg16 + (size_t)NPTS * TDIM * FDIM;

  prep_kernel<<<96, 256, 0, stream>>>(W1, Wfc, W2, w1h, wfh, w2h);
  conv1_kernel<<<NPTS / NG, 256, 0, stream>>>(x, w1h, b1, h16, h16t);
  gather_kernel<<<GNB, 256, 0, stream>>>(h16t, nidx, nmask, agg16);
  fc_kernel<<<NPTS / NG, 256, 0, stream>>>(h16, agg16, wfh, bfc, z16);
  conv2_kernel<<<NPTS / NG, 256, 0, stream>>>(z16, w2h, b2, out);
}

// Round 13
// 294.656 us; speedup vs baseline: 7.0424x; 1.1024x over previous
//
#include <hip/hip_runtime.h>
#include <cstddef>
#include <cstdint>

#define NPTS 10000
#define TDIM 64
#define CINDIM 64
#define FDIM 64
#define HIDDIM 128
#define SDIM 8
#define NG 4     // n's per block in matmul kernels
#define GNB 4000 // gather blocks (500 per XCD)

typedef _Float16 f16;
typedef _Float16 f16x2 __attribute__((ext_vector_type(2)));
typedef _Float16 f16x4 __attribute__((ext_vector_type(4)));
typedef _Float16 f16x8 __attribute__((ext_vector_type(8)));
typedef float f32x4 __attribute__((ext_vector_type(4)));
typedef float f32x16 __attribute__((ext_vector_type(16)));

#define MFMA32(a, b, c) __builtin_amdgcn_mfma_f32_32x32x16_f16((a), (b), (c), 0, 0, 0)

static __device__ __forceinline__ f16x2 pk(float a, float b) {
  return __builtin_bit_cast(f16x2, __builtin_amdgcn_cvt_pkrtz(a, b));
}
static __device__ __forceinline__ f16x4 pack4(f32x4 p) {
  f16x2 h0 = pk(p[0], p[1]), h1 = pk(p[2], p[3]);
  return __builtin_shufflevector(h0, h1, 0, 1, 2, 3);
}
static __device__ __forceinline__ f16x4 pack4_relu(f32x4 v, f32x4 bias) {
  f16x4 r;
  r[0] = (f16)fmaxf(v[0] + bias[0], 0.f);
  r[1] = (f16)fmaxf(v[1] + bias[1], 0.f);
  r[2] = (f16)fmaxf(v[2] + bias[2], 0.f);
  r[3] = (f16)fmaxf(v[3] + bias[3], 0.f);
  return r;
}

// ---------------------------------------------------------------------------
// prep: round weights to f16 and pre-shuffle into 32x32x16 A-frag order:
// lane l holds A[row=l&31][kk=(l>>5)*8+j]. Storage [slice][ks][lane][j],
// kk = ks*16+(l>>5)*8+j.
//   conv1 kk = k*64 + c   (K=192, 12 ks, 2 slices)
//   fc    kk = c          (K=128,  8 ks, 4 slices)
//   conv2 kk = k*128 + c  (K=384, 24 ks, 2 slices)
// ---------------------------------------------------------------------------
__global__ __launch_bounds__(256) void prep_kernel(
    const float* __restrict__ W1, const float* __restrict__ Wfc,
    const float* __restrict__ W2, f16* __restrict__ w1h,
    f16* __restrict__ wfh, f16* __restrict__ w2h) {
  const int idx = blockIdx.x * 256 + threadIdx.x;
  const int j = idx & 7;
  if (idx < 2 * 12 * 512) {  // w1
    const int s = idx / 6144, rem = idx % 6144;
    const int ks = rem / 512, l = (rem % 512) >> 3;
    const int kk = ks * 16 + ((l >> 5) << 3) + j;
    const int k = kk >> 6, c = kk & 63, f = s * 32 + (l & 31);
    w1h[idx] = (f16)W1[f * 192 + c * 3 + k];
  }
  if (idx < 4 * 8 * 512) {  // wfc
    const int s = idx / 4096, rem = idx % 4096;
    const int ks = rem / 512, l = (rem % 512) >> 3;
    const int kk = ks * 16 + ((l >> 5) << 3) + j;
    const int hc = s * 32 + (l & 31);
    wfh[idx] = (f16)Wfc[hc * 128 + kk];
  }
  if (idx < 2 * 24 * 512) {  // w2
    const int s = idx / 12288, rem = idx % 12288;
    const int ks = rem / 512, l = (rem % 512) >> 3;
    const int kk = ks * 16 + ((l >> 5) << 3) + j;
    const int k = kk >> 7, c = kk & 127, f = s * 32 + (l & 31);
    w2h[idx] = (f16)W2[f * 384 + c * 3 + k];
  }
}

// ---------------------------------------------------------------------------
// conv1: relu(b1 + sum_{k,c} W1[f,c,k] x[n, t-4+2k, c]).
// LDS-staged: x[n] tile (64x64 fp32) loaded coalesced, packed to f16 into
// xs[68][72] (rows 0-3 = causal zero pad). Wave w: M-slice s=w>>1, t-half
// th=w&1. Writes h ONLY t-major (h16t): gather reads it randomly (L2-local
// slabs) and fc stages whole 128B rows from it (full-line transactions, so
// the n-major copy was pure write overhead -- round-13 change).
// ---------------------------------------------------------------------------
__global__ __launch_bounds__(256) void conv1_kernel(
    const float* __restrict__ x, const f16* __restrict__ w1h,
    const float* __restrict__ b1, f16* __restrict__ h16t) {
  __shared__ f16 xs[68 * 72];
  const int tid = threadIdx.x;
  const int w = tid >> 6, lane = tid & 63;
  const int s = w >> 1, th = w & 1;
  const int rl = lane & 31, hi = lane >> 5;
  f16x8 wh[12];
#pragma unroll
  for (int ks = 0; ks < 12; ++ks)
    wh[ks] = *(const f16x8*)&w1h[((s * 12 + ks) * 64 + lane) * 8];
  f32x4 bias[4];
#pragma unroll
  for (int q = 0; q < 4; ++q) bias[q] = *(const f32x4*)&b1[s * 32 + 8 * q + 4 * hi];
  // rows 0-3 (causal pad) = 288 f16 = 144 f16x2; 144 <= 256 threads -> full.
  if (tid < 144) ((f16x2*)xs)[tid] = (f16x2){(f16)0, (f16)0};

  for (int g = 0; g < NG; ++g) {
    const int n = blockIdx.x * NG + g;
    const float* xn = x + (size_t)n * (TDIM * CINDIM);
    if (g) __syncthreads();  // previous compute done before overwrite
#pragma unroll
    for (int pass = 0; pass < 4; ++pass) {  // 64 rows x 16 chunks of 4 fp32
      const int idx = pass * 256 + tid;
      const int row = idx >> 4, c4 = (idx & 15) * 4;
      const f32x4 v = *(const f32x4*)&xn[row * 64 + c4];
      *(f16x4*)&xs[(row + 4) * 72 + c4] = pack4(v);
    }
    __syncthreads();

    f32x16 acc;
#pragma unroll
    for (int i = 0; i < 16; ++i) acc[i] = 0.f;
#pragma unroll
    for (int ks = 0; ks < 12; ++ks) {
      const int k = ks >> 2;
      const int c0 = (ks & 3) * 16 + hi * 8;
      const f16x8 b = *(const f16x8*)&xs[(th * 32 + rl + 2 * k) * 72 + c0];
      acc = MFMA32(wh[ks], b, acc);
    }
    const int t = th * 32 + rl;
    f16* hrowt = h16t + ((size_t)t * NPTS + n) * 64;
#pragma unroll
    for (int q = 0; q < 4; ++q) {
      const f32x4 sub = {acc[4 * q], acc[4 * q + 1], acc[4 * q + 2], acc[4 * q + 3]};
      *(f16x4*)&hrowt[s * 32 + 8 * q + 4 * hi] = pack4_relu(sub, bias[q]);
    }
  }
}

// ---------------------------------------------------------------------------
// gather: agg[n][t][:] = masked-mean_s h16t[t][idx[t,n,s]][:] (fallback self).
// Quarter-wave per (t,n) pair: lane = q4*16+sl reads 8B of pair q4's rows ->
// one wave64 gather instruction serves 4 pairs (4x128B rows). idx/mask for
// all 4 pairs loaded by one instruction and broadcast via __shfl. Walk
// (stride 8000/iter, 10 iters) keeps each XCD inside its 8-t slab set.
// ---------------------------------------------------------------------------
__global__ __launch_bounds__(256) void gather_kernel(
    const f16* __restrict__ h16t, const int* __restrict__ nidx,
    const int* __restrict__ nmask, f16* __restrict__ agg16) {
  const int tid = threadIdx.x;
  const int wv = tid >> 6, lane = tid & 63;
  const int q4 = lane >> 4, sl = lane & 15;             // quarter, sublane
  const int xcd = blockIdx.x & 7, q = blockIdx.x >> 3;  // q in [0,500)
  const uint2* h64 = (const uint2*)h16t;                // 8B units
  uint2* agg64 = (uint2*)agg16;

  int t = xcd * 8;
  int n = (q * 4 + wv) * 4;            // quad base in [0,8000), 4-aligned
  const int eo = q4 * 8 + (lane & 7);  // this lane's idx/mask element
  int ci, cm;
  {
    const size_t pr = ((size_t)t * NPTS + n) * SDIM;
    ci = nidx[pr + eo];
    cm = nmask[pr + eo];
  }
  for (int j = 0; j < 10; ++j) {
    int tn = t, nn = n + 8000;
    if (nn >= NPTS) { nn -= NPTS; ++tn; }  // stride < NPTS: at most one wrap
    int pi = 0, pm = 0;
    if (j + 1 < 10) {  // prefetch next quad's idx/mask
      const size_t pr = ((size_t)tn * NPTS + nn) * SDIM;
      pi = nidx[pr + eo];
      pm = nmask[pr + eo];
    }
    const uint32_t tb = (uint32_t)t * (NPTS * 16) + sl;  // uint2 units
    uint2 u[8];
#pragma unroll
    for (int s = 0; s < SDIM; ++s) {
      const int is = __shfl(ci, (lane & 48) + s, 64);
      u[s] = h64[tb + (uint32_t)is * 16u];
    }
    float a0 = 0.f, a1 = 0.f, a2 = 0.f, a3 = 0.f, cnt = 0.f;
#pragma unroll
    for (int s = 0; s < SDIM; ++s) {
      const float m = (__shfl(cm, (lane & 48) + s, 64) != 0) ? 1.f : 0.f;
      const f16x2 lo = __builtin_bit_cast(f16x2, u[s].x);
      const f16x2 hi = __builtin_bit_cast(f16x2, u[s].y);
      a0 = fmaf(m, (float)lo[0], a0);
      a1 = fmaf(m, (float)lo[1], a1);
      a2 = fmaf(m, (float)hi[0], a2);
      a3 = fmaf(m, (float)hi[1], a3);
      cnt += m;
    }
    uint2 outv;
    if (cnt > 0.f) {
      const float inv = 1.f / cnt;
      const f16x4 o4 = pack4((f32x4){a0 * inv, a1 * inv, a2 * inv, a3 * inv});
      outv = __builtin_bit_cast(uint2, o4);
    } else {  // fallback: self row (exec-masked; skipped when no lane needs it)
      outv = h64[tb + (uint32_t)(n + q4) * 16u];
    }
    agg64[((size_t)(n + q4) * 64 + t) * 16 + sl] = outv;
    ci = pi; cm = pm; t = tn; n = nn;
  }
}

// ---------------------------------------------------------------------------
// fc: z[n][t][hc] = relu(bfc + sum_c [h|agg][n,t,c] Wfc[hc,c]).
// LDS-staged: hs staged from t-major h16t (row (t,n) = one full 128B line,
// 8 thr x 16B -> transaction-dense); as from n-major agg16. Wave w: M-pair
// mp=w>>1 (hc slices {2mp,2mp+1}), t-half th=w&1.
// ---------------------------------------------------------------------------
__global__ __launch_bounds__(256) void fc_kernel(
    const f16* __restrict__ h16t, const f16* __restrict__ agg16,
    const f16* __restrict__ wfh, const float* __restrict__ bfc,
    f16* __restrict__ z16) {
  __shared__ f16 hs[64 * 72];
  __shared__ f16 as2[64 * 72];
  const int tid = threadIdx.x;
  const int w = tid >> 6, lane = tid & 63;
  const int mp = w >> 1, th = w & 1;
  const int rl = lane & 31, hi = lane >> 5;
  f16x8 whA[8], whB[8];
#pragma unroll
  for (int ks = 0; ks < 8; ++ks) {
    whA[ks] = *(const f16x8*)&wfh[(((2 * mp) * 8 + ks) * 64 + lane) * 8];
    whB[ks] = *(const f16x8*)&wfh[(((2 * mp + 1) * 8 + ks) * 64 + lane) * 8];
  }
  f32x4 biasA[4], biasB[4];
#pragma unroll
  for (int q = 0; q < 4; ++q) {
    biasA[q] = *(const f32x4*)&bfc[(2 * mp) * 32 + 8 * q + 4 * hi];
    biasB[q] = *(const f32x4*)&bfc[(2 * mp + 1) * 32 + 8 * q + 4 * hi];
  }
  const int t = th * 32 + rl;
  for (int g = 0; g < NG; ++g) {
    const int n = blockIdx.x * NG + g;
    if (g) __syncthreads();
#pragma unroll
    for (int pass = 0; pass < 2; ++pass) {  // 64 rows x 8 chunks of 8 f16
      const int idx = pass * 256 + tid;
      const int row = idx >> 3, c8 = (idx & 7) * 8;
      *(f16x8*)&hs[row * 72 + c8] =
          *(const f16x8*)&h16t[((size_t)row * NPTS + n) * 64 + c8];
      *(f16x8*)&as2[row * 72 + c8] =
          *(const f16x8*)&agg16[((size_t)n * 64 + row) * 64 + c8];
    }
    __syncthreads();

    f32x16 accA, accB;
#pragma unroll
    for (int i = 0; i < 16; ++i) { accA[i] = 0.f; accB[i] = 0.f; }
    f16x8 bf[8];
#pragma unroll
    for (int ks = 0; ks < 8; ++ks) {
      const int c0 = (ks & 3) * 16 + hi * 8;
      bf[ks] = (ks < 4) ? *(const f16x8*)&hs[t * 72 + c0]
                        : *(const f16x8*)&as2[t * 72 + c0];
    }
#pragma unroll
    for (int ks = 0; ks < 8; ++ks) accA = MFMA32(whA[ks], bf[ks], accA);
#pragma unroll
    for (int ks = 0; ks < 8; ++ks) accB = MFMA32(whB[ks], bf[ks], accB);
    f16* zrow = z16 + ((size_t)n * 64 + t) * 128;
#pragma unroll
    for (int q = 0; q < 4; ++q) {
      const f32x4 sa = {accA[4 * q], accA[4 * q + 1], accA[4 * q + 2], accA[4 * q + 3]};
      const f32x4 sb = {accB[4 * q], accB[4 * q + 1], accB[4 * q + 2], accB[4 * q + 3]};
      *(f16x4*)&zrow[(2 * mp) * 32 + 8 * q + 4 * hi] = pack4_relu(sa, biasA[q]);
      *(f16x4*)&zrow[(2 * mp + 1) * 32 + 8 * q + 4 * hi] = pack4_relu(sb, biasB[q]);
    }
  }
}

// ---------------------------------------------------------------------------
// conv2: out[n,t,f] = relu(b2 + sum_{k,c} W2[f,c,k] z[n, t-4+2k, c]). fp32 out.
// LDS-staged: zs[68][136] (rows 0-3 zero pad = 544 f16 = 136 f16x4, within
// 256 threads). 24 ks.
// ---------------------------------------------------------------------------
__global__ __launch_bounds__(256) void conv2_kernel(
    const f16* __restrict__ z16, const f16* __restrict__ w2h,
    const float* __restrict__ b2, float* __restrict__ out) {
  __shared__ f16 zs[68 * 136];
  const int tid = threadIdx.x;
  const int w = tid >> 6, lane = tid & 63;
  const int s = w >> 1, th = w & 1;
  const int rl = lane & 31, hi = lane >> 5;
  f16x8 wh[24];
#pragma unroll
  for (int ks = 0; ks < 24; ++ks)
    wh[ks] = *(const f16x8*)&w2h[((s * 24 + ks) * 64 + lane) * 8];
  f32x4 bias[4];
#pragma unroll
  for (int q = 0; q < 4; ++q) bias[q] = *(const f32x4*)&b2[s * 32 + 8 * q + 4 * hi];
  if (tid < 136) ((f16x4*)zs)[tid] = (f16x4){(f16)0, (f16)0, (f16)0, (f16)0};

  for (int g = 0; g < NG; ++g) {
    const int n = blockIdx.x * NG + g;
    const f16* zn = z16 + (size_t)n * (TDIM * HIDDIM);
    if (g) __syncthreads();
#pragma unroll
    for (int pass = 0; pass < 4; ++pass) {  // 64 rows x 16 chunks of 8 f16
      const int idx = pass * 256 + tid;
      const int row = idx >> 4, c8 = (idx & 15) * 8;
      *(f16x8*)&zs[(row + 4) * 136 + c8] = *(const f16x8*)&zn[row * 128 + c8];
    }
    __syncthreads();

    f32x16 acc;
#pragma unroll
    for (int i = 0; i < 16; ++i) acc[i] = 0.f;
#pragma unroll
    for (int ks = 0; ks < 24; ++ks) {
      const int k = ks >> 3;
      const int c0 = (ks & 7) * 16 + hi * 8;
      const f16x8 b = *(const f16x8*)&zs[(th * 32 + rl + 2 * k) * 136 + c0];
      acc = MFMA32(wh[ks], b, acc);
    }
    const int t = th * 32 + rl;
    float* orow = out + ((size_t)n * 64 + t) * 64;
#pragma unroll
    for (int q = 0; q < 4; ++q) {
      f32x4 v;
      v[0] = fmaxf(acc[4 * q + 0] + bias[q][0], 0.f);
      v[1] = fmaxf(acc[4 * q + 1] + bias[q][1], 0.f);
      v[2] = fmaxf(acc[4 * q + 2] + bias[q][2], 0.f);
      v[3] = fmaxf(acc[4 * q + 3] + bias[q][3], 0.f);
      *(f32x4*)&orow[s * 32 + 8 * q + 4 * hi] = v;
    }
  }
}

// ---------------------------------------------------------------------------
// Workspace (f16 units): w1h 12288 | wfh 16384 | w2h 24576 |
//   h16t 41M (t-major) | agg16 41M | z16 82M  ~328 MB.
// ---------------------------------------------------------------------------
extern "C" void kernel_launch(void* const* d_in, const int* in_sizes, int n_in,
                              void* d_out, int out_size, void* d_ws, size_t ws_size,
                              hipStream_t stream) {
  (void)in_sizes; (void)n_in; (void)out_size; (void)ws_size;
  const float* x   = (const float*)d_in[0];
  const float* W1  = (const float*)d_in[1];
  const float* b1  = (const float*)d_in[2];
  const float* Wfc = (const float*)d_in[3];
  const float* bfc = (const float*)d_in[4];
  const float* W2  = (const float*)d_in[5];
  const float* b2  = (const float*)d_in[6];
  const int* nidx  = (const int*)d_in[7];
  const int* nmask = (const int*)d_in[8];
  float* out = (float*)d_out;

  f16* wsf = (f16*)d_ws;
  f16* w1h = wsf;
  f16* wfh = w1h + 12288;
  f16* w2h = wfh + 16384;
  f16* h16t = w2h + 24576;
  f16* agg16 = h16t + (size_t)NPTS * TDIM * FDIM;
  f16* z16 = agg16 + (size_t)NPTS * TDIM * FDIM;

  prep_kernel<<<96, 256, 0, stream>>>(W1, Wfc, W2, w1h, wfh, w2h);
  conv1_kernel<<<NPTS / NG, 256, 0, stream>>>(x, w1h, b1, h16t);
  gather_kernel<<<GNB, 256, 0, stream>>>(h16t, nidx, nmask, agg16);
  fc_kernel<<<NPTS / NG, 256, 0, stream>>>(h16t, agg16, wfh, bfc, z16);
  conv2_kernel<<<NPTS / NG, 256, 0, stream>>>(z16, w2h, b2, out);
}

// Round 14
// 214.854 us; speedup vs baseline: 9.6581x; 1.3714x over previous
//
#include <hip/hip_runtime.h>
#include <cstddef>
#include <cstdint>

#define NPTS 10000
#define TDIM 64
#define CINDIM 64
#define FDIM 64
#define HIDDIM 128
#define SDIM 8
#define NG 4     // n's per block in matmul kernels
#define GNB 2000 // gather blocks (250 per XCD)

typedef _Float16 f16;
typedef _Float16 f16x2 __attribute__((ext_vector_type(2)));
typedef _Float16 f16x4 __attribute__((ext_vector_type(4)));
typedef _Float16 f16x8 __attribute__((ext_vector_type(8)));
typedef float f32x4 __attribute__((ext_vector_type(4)));
typedef float f32x16 __attribute__((ext_vector_type(16)));

#define MFMA32(a, b, c) __builtin_amdgcn_mfma_f32_32x32x16_f16((a), (b), (c), 0, 0, 0)

static __device__ __forceinline__ f16x2 pk(float a, float b) {
  return __builtin_bit_cast(f16x2, __builtin_amdgcn_cvt_pkrtz(a, b));
}
static __device__ __forceinline__ f16x4 pack4(f32x4 p) {
  f16x2 h0 = pk(p[0], p[1]), h1 = pk(p[2], p[3]);
  return __builtin_shufflevector(h0, h1, 0, 1, 2, 3);
}
static __device__ __forceinline__ f16x4 pack4_relu(f32x4 v, f32x4 bias) {
  f16x4 r;
  r[0] = (f16)fmaxf(v[0] + bias[0], 0.f);
  r[1] = (f16)fmaxf(v[1] + bias[1], 0.f);
  r[2] = (f16)fmaxf(v[2] + bias[2], 0.f);
  r[3] = (f16)fmaxf(v[3] + bias[3], 0.f);
  return r;
}

// ---------------------------------------------------------------------------
// prep: round weights to f16 and pre-shuffle into 32x32x16 A-frag order:
// lane l holds A[row=l&31][kk=(l>>5)*8+j]. Storage [slice][ks][lane][j],
// kk = ks*16+(l>>5)*8+j.
//   conv1 kk = k*64 + c   (K=192, 12 ks, 2 slices)
//   fc    kk = c          (K=128,  8 ks, 4 slices)
//   conv2 kk = k*128 + c  (K=384, 24 ks, 2 slices)
// ---------------------------------------------------------------------------
__global__ __launch_bounds__(256) void prep_kernel(
    const float* __restrict__ W1, const float* __restrict__ Wfc,
    const float* __restrict__ W2, f16* __restrict__ w1h,
    f16* __restrict__ wfh, f16* __restrict__ w2h) {
  const int idx = blockIdx.x * 256 + threadIdx.x;
  const int j = idx & 7;
  if (idx < 2 * 12 * 512) {  // w1
    const int s = idx / 6144, rem = idx % 6144;
    const int ks = rem / 512, l = (rem % 512) >> 3;
    const int kk = ks * 16 + ((l >> 5) << 3) + j;
    const int k = kk >> 6, c = kk & 63, f = s * 32 + (l & 31);
    w1h[idx] = (f16)W1[f * 192 + c * 3 + k];
  }
  if (idx < 4 * 8 * 512) {  // wfc
    const int s = idx / 4096, rem = idx % 4096;
    const int ks = rem / 512, l = (rem % 512) >> 3;
    const int kk = ks * 16 + ((l >> 5) << 3) + j;
    const int hc = s * 32 + (l & 31);
    wfh[idx] = (f16)Wfc[hc * 128 + kk];
  }
  if (idx < 2 * 24 * 512) {  // w2
    const int s = idx / 12288, rem = idx % 12288;
    const int ks = rem / 512, l = (rem % 512) >> 3;
    const int kk = ks * 16 + ((l >> 5) << 3) + j;
    const int k = kk >> 7, c = kk & 127, f = s * 32 + (l & 31);
    w2h[idx] = (f16)W2[f * 384 + c * 3 + k];
  }
}

// ---------------------------------------------------------------------------
// conv1: relu(b1 + sum_{k,c} W1[f,c,k] x[n, t-4+2k, c]).
// LDS-staged: x[n] tile (64x64 fp32) loaded coalesced, packed to f16 into
// xs[68][72] (rows 0-3 = causal zero pad). Wave w: M-slice s=w>>1, t-half
// th=w&1. Writes h t-major only (h16t).
// ---------------------------------------------------------------------------
__global__ __launch_bounds__(256) void conv1_kernel(
    const float* __restrict__ x, const f16* __restrict__ w1h,
    const float* __restrict__ b1, f16* __restrict__ h16t) {
  __shared__ f16 xs[68 * 72];
  const int tid = threadIdx.x;
  const int w = tid >> 6, lane = tid & 63;
  const int s = w >> 1, th = w & 1;
  const int rl = lane & 31, hi = lane >> 5;
  f16x8 wh[12];
#pragma unroll
  for (int ks = 0; ks < 12; ++ks)
    wh[ks] = *(const f16x8*)&w1h[((s * 12 + ks) * 64 + lane) * 8];
  f32x4 bias[4];
#pragma unroll
  for (int q = 0; q < 4; ++q) bias[q] = *(const f32x4*)&b1[s * 32 + 8 * q + 4 * hi];
  // rows 0-3 (causal pad) = 288 f16 = 144 f16x2; 144 <= 256 threads -> full.
  if (tid < 144) ((f16x2*)xs)[tid] = (f16x2){(f16)0, (f16)0};

  for (int g = 0; g < NG; ++g) {
    const int n = blockIdx.x * NG + g;
    const float* xn = x + (size_t)n * (TDIM * CINDIM);
    if (g) __syncthreads();  // previous compute done before overwrite
#pragma unroll
    for (int pass = 0; pass < 4; ++pass) {  // 64 rows x 16 chunks of 4 fp32
      const int idx = pass * 256 + tid;
      const int row = idx >> 4, c4 = (idx & 15) * 4;
      const f32x4 v = *(const f32x4*)&xn[row * 64 + c4];
      *(f16x4*)&xs[(row + 4) * 72 + c4] = pack4(v);
    }
    __syncthreads();

    f32x16 acc;
#pragma unroll
    for (int i = 0; i < 16; ++i) acc[i] = 0.f;
#pragma unroll
    for (int ks = 0; ks < 12; ++ks) {
      const int k = ks >> 2;
      const int c0 = (ks & 3) * 16 + hi * 8;
      const f16x8 b = *(const f16x8*)&xs[(th * 32 + rl + 2 * k) * 72 + c0];
      acc = MFMA32(wh[ks], b, acc);
    }
    const int t = th * 32 + rl;
    f16* hrowt = h16t + ((size_t)t * NPTS + n) * 64;
#pragma unroll
    for (int q = 0; q < 4; ++q) {
      const f32x4 sub = {acc[4 * q], acc[4 * q + 1], acc[4 * q + 2], acc[4 * q + 3]};
      *(f16x4*)&hrowt[s * 32 + 8 * q + 4 * hi] = pack4_relu(sub, bias[q]);
    }
  }
}

// ---------------------------------------------------------------------------
// gather: agg[n][t][:] = masked-mean_s h16t[t][idx[t,n,s]][:] (fallback self).
// Octet per (t,n) pair: lane = oct*8+sl8; each octet owns one pair, lane
// reads 16B (dwordx4) -> one wave gather instruction serves 8 pairs. idx/mask
// for the octet-group = 64 elements = ONE coalesced wave load each
// (nidx[(t*NPTS+n)*8 + lane]), broadcast via __shfl(v, oct*8+s). VMEM per
// 8 pairs: 11 (was 22). Walk: 250 blocks/XCD, stride 8000, 10 iters; o-span
// 8000 -> <=2 concurrent t-slabs/XCD (2.6MB < 4MB L2); octet never straddles
// t (10000 % 8 == 0, bases 8-aligned, stride 8000 % 8 == 0).
// ---------------------------------------------------------------------------
__global__ __launch_bounds__(256) void gather_kernel(
    const f16* __restrict__ h16t, const int* __restrict__ nidx,
    const int* __restrict__ nmask, f16* __restrict__ agg16) {
  const int tid = threadIdx.x;
  const int wv = tid >> 6, lane = tid & 63;
  const int oct = lane >> 3, sl8 = lane & 7;            // octet, sublane
  const int xcd = blockIdx.x & 7, q = blockIdx.x >> 3;  // q in [0,250)
  const uint4* h128 = (const uint4*)h16t;               // 16B units
  uint4* agg128 = (uint4*)agg16;

  int t = xcd * 8;
  int n = (q * 4 + wv) * 8;  // octet base in [0,8000), 8-aligned
  int ci, cm;
  {
    const size_t pr = ((size_t)t * NPTS + n) * SDIM;
    ci = nidx[pr + lane];
    cm = nmask[pr + lane];
  }
  for (int j = 0; j < 10; ++j) {
    int tn = t, nn = n + 8000;
    if (nn >= NPTS) { nn -= NPTS; ++tn; }  // stride < NPTS: at most one wrap
    int pi = 0, pm = 0;
    if (j + 1 < 10) {  // prefetch next octet-group's idx/mask
      const size_t pr = ((size_t)tn * NPTS + nn) * SDIM;
      pi = nidx[pr + lane];
      pm = nmask[pr + lane];
    }
    const uint32_t tb = (uint32_t)t * (NPTS * 8) + sl8;  // uint4 units
    uint4 u[8];
#pragma unroll
    for (int s = 0; s < SDIM; ++s) {
      const int is = __shfl(ci, oct * 8 + s, 64);
      u[s] = h128[tb + (uint32_t)is * 8u];
    }
    float a[8] = {0.f, 0.f, 0.f, 0.f, 0.f, 0.f, 0.f, 0.f};
    float cnt = 0.f;
#pragma unroll
    for (int s = 0; s < SDIM; ++s) {
      const float m = (__shfl(cm, oct * 8 + s, 64) != 0) ? 1.f : 0.f;
      const f16x2 p0 = __builtin_bit_cast(f16x2, u[s].x);
      const f16x2 p1 = __builtin_bit_cast(f16x2, u[s].y);
      const f16x2 p2 = __builtin_bit_cast(f16x2, u[s].z);
      const f16x2 p3 = __builtin_bit_cast(f16x2, u[s].w);
      a[0] = fmaf(m, (float)p0[0], a[0]);
      a[1] = fmaf(m, (float)p0[1], a[1]);
      a[2] = fmaf(m, (float)p1[0], a[2]);
      a[3] = fmaf(m, (float)p1[1], a[3]);
      a[4] = fmaf(m, (float)p2[0], a[4]);
      a[5] = fmaf(m, (float)p2[1], a[5]);
      a[6] = fmaf(m, (float)p3[0], a[6]);
      a[7] = fmaf(m, (float)p3[1], a[7]);
      cnt += m;
    }
    uint4 outv;
    if (cnt > 0.f) {
      const float inv = 1.f / cnt;
      const f16x4 lo4 = pack4((f32x4){a[0] * inv, a[1] * inv, a[2] * inv, a[3] * inv});
      const f16x4 hi4 = pack4((f32x4){a[4] * inv, a[5] * inv, a[6] * inv, a[7] * inv});
      const uint2 lo = __builtin_bit_cast(uint2, lo4);
      const uint2 hi = __builtin_bit_cast(uint2, hi4);
      outv.x = lo.x; outv.y = lo.y; outv.z = hi.x; outv.w = hi.y;
    } else {  // fallback: self row (exec-masked)
      outv = h128[tb + (uint32_t)(n + oct) * 8u];
    }
    agg128[((size_t)(n + oct) * 64 + t) * 8 + sl8] = outv;
    ci = pi; cm = pm; t = tn; n = nn;
  }
}

// ---------------------------------------------------------------------------
// fused fc+conv2: z never touches global (saves its 328MB round-trip).
// Per g: stage hs/as -> fc MFMA (wave w owns hc slice [32w,32w+32), both
// t-halves) writes relu(z) f16 into zs[68][136] LDS (rows 0-3 = causal pad)
// -> barrier -> conv2 MFMA (wave w: M-slice w>>1, t-half w&1) -> out fp32.
// Numerics identical to the split version (z rounds to f16 either way).
// ---------------------------------------------------------------------------
__global__ __launch_bounds__(256) void fc_conv2_kernel(
    const f16* __restrict__ h16t, const f16* __restrict__ agg16,
    const f16* __restrict__ wfh, const float* __restrict__ bfc,
    const f16* __restrict__ w2h, const float* __restrict__ b2,
    float* __restrict__ out) {
  __shared__ f16 hs[64 * 72];
  __shared__ f16 as2[64 * 72];
  __shared__ f16 zs[68 * 136];
  const int tid = threadIdx.x;
  const int w = tid >> 6, lane = tid & 63;
  const int rl = lane & 31, hi = lane >> 5;
  f16x8 whf[8];
#pragma unroll
  for (int ks = 0; ks < 8; ++ks)
    whf[ks] = *(const f16x8*)&wfh[((w * 8 + ks) * 64 + lane) * 8];
  f32x4 biasf[4];
#pragma unroll
  for (int q = 0; q < 4; ++q)
    biasf[q] = *(const f32x4*)&bfc[w * 32 + 8 * q + 4 * hi];
  const int s2 = w >> 1, th2 = w & 1;
  f16x8 wh2[24];
#pragma unroll
  for (int ks = 0; ks < 24; ++ks)
    wh2[ks] = *(const f16x8*)&w2h[((s2 * 24 + ks) * 64 + lane) * 8];
  f32x4 bias2[4];
#pragma unroll
  for (int q = 0; q < 4; ++q)
    bias2[q] = *(const f32x4*)&b2[s2 * 32 + 8 * q + 4 * hi];
  // zs rows 0-3 (causal pad) = 544 f16 = 136 f16x4, within 256 threads.
  if (tid < 136) ((f16x4*)zs)[tid] = (f16x4){(f16)0, (f16)0, (f16)0, (f16)0};

  for (int g = 0; g < NG; ++g) {
    const int n = blockIdx.x * NG + g;
    if (g) __syncthreads();  // prev conv2 done with zs, prev fc done with hs/as
#pragma unroll
    for (int pass = 0; pass < 2; ++pass) {  // 64 rows x 8 chunks of 8 f16
      const int idx = pass * 256 + tid;
      const int row = idx >> 3, c8 = (idx & 7) * 8;
      *(f16x8*)&hs[row * 72 + c8] =
          *(const f16x8*)&h16t[((size_t)row * NPTS + n) * 64 + c8];
      *(f16x8*)&as2[row * 72 + c8] =
          *(const f16x8*)&agg16[((size_t)n * 64 + row) * 64 + c8];
    }
    __syncthreads();

    // fc phase: z[t][32w..32w+32) for all 64 t
#pragma unroll
    for (int tf = 0; tf < 2; ++tf) {
      f32x16 accf;
#pragma unroll
      for (int i = 0; i < 16; ++i) accf[i] = 0.f;
      const int t = tf * 32 + rl;
#pragma unroll
      for (int ks = 0; ks < 8; ++ks) {
        const int c0 = (ks & 3) * 16 + hi * 8;
        const f16x8 b = (ks < 4) ? *(const f16x8*)&hs[t * 72 + c0]
                                 : *(const f16x8*)&as2[t * 72 + c0];
        accf = MFMA32(whf[ks], b, accf);
      }
#pragma unroll
      for (int q = 0; q < 4; ++q) {
        const f32x4 sub = {accf[4 * q], accf[4 * q + 1], accf[4 * q + 2], accf[4 * q + 3]};
        *(f16x4*)&zs[(t + 4) * 136 + w * 32 + 8 * q + 4 * hi] =
            pack4_relu(sub, biasf[q]);
      }
    }
    __syncthreads();

    // conv2 phase
    f32x16 acc;
#pragma unroll
    for (int i = 0; i < 16; ++i) acc[i] = 0.f;
#pragma unroll
    for (int ks = 0; ks < 24; ++ks) {
      const int k = ks >> 3;
      const int c0 = (ks & 7) * 16 + hi * 8;
      const f16x8 b = *(const f16x8*)&zs[(th2 * 32 + rl + 2 * k) * 136 + c0];
      acc = MFMA32(wh2[ks], b, acc);
    }
    const int t = th2 * 32 + rl;
    float* orow = out + ((size_t)n * 64 + t) * 64;
#pragma unroll
    for (int q = 0; q < 4; ++q) {
      f32x4 v;
      v[0] = fmaxf(acc[4 * q + 0] + bias2[q][0], 0.f);
      v[1] = fmaxf(acc[4 * q + 1] + bias2[q][1], 0.f);
      v[2] = fmaxf(acc[4 * q + 2] + bias2[q][2], 0.f);
      v[3] = fmaxf(acc[4 * q + 3] + bias2[q][3], 0.f);
      *(f32x4*)&orow[s2 * 32 + 8 * q + 4 * hi] = v;
    }
  }
}

// ---------------------------------------------------------------------------
// Workspace (f16 units): w1h 12288 | wfh 16384 | w2h 24576 |
//   h16t 41M (t-major) | agg16 41M   ~164 MB (z eliminated by fusion).
// ---------------------------------------------------------------------------
extern "C" void kernel_launch(void* const* d_in, const int* in_sizes, int n_in,
                              void* d_out, int out_size, void* d_ws, size_t ws_size,
                              hipStream_t stream) {
  (void)in_sizes; (void)n_in; (void)out_size; (void)ws_size;
  const float* x   = (const float*)d_in[0];
  const float* W1  = (const float*)d_in[1];
  const float* b1  = (const float*)d_in[2];
  const float* Wfc = (const float*)d_in[3];
  const float* bfc = (const float*)d_in[4];
  const float* W2  = (const float*)d_in[5];
  const float* b2  = (const float*)d_in[6];
  const int* nidx  = (const int*)d_in[7];
  const int* nmask = (const int*)d_in[8];
  float* out = (float*)d_out;

  f16* wsf = (f16*)d_ws;
  f16* w1h = wsf;
  f16* wfh = w1h + 12288;
  f16* w2h = wfh + 16384;
  f16* h16t = w2h + 24576;
  f16* agg16 = h16t + (size_t)NPTS * TDIM * FDIM;

  prep_kernel<<<96, 256, 0, stream>>>(W1, Wfc, W2, w1h, wfh, w2h);
  conv1_kernel<<<NPTS / NG, 256, 0, stream>>>(x, w1h, b1, h16t);
  gather_kernel<<<GNB, 256, 0, stream>>>(h16t, nidx, nmask, agg16);
  fc_conv2_kernel<<<NPTS / NG, 256, 0, stream>>>(h16t, agg16, wfh, bfc,
                                                 w2h, b2, out);
}